// Round 4
// baseline (377.822 us; speedup 1.0000x reference)
//
#include <hip/hip_runtime.h>
#include <hip/hip_bf16.h>
#include <math.h>

#define B_ 8
#define S_ 1024
#define D_ 1024
#define H_ 16
#define HD_ 64

typedef __bf16 bf16x8 __attribute__((ext_vector_type(8)));
typedef __bf16 bf16x4 __attribute__((ext_vector_type(4)));
typedef float f32x4 __attribute__((ext_vector_type(4)));

__device__ __forceinline__ void gld_lds16(const __bf16* g, __bf16* l) {
  __builtin_amdgcn_global_load_lds(
      (const __attribute__((address_space(1))) void*)g,
      (__attribute__((address_space(3))) void*)l, 16, 0, 0);
}

// ---------------- LayerNorm: fp32 in, bf16 out ----------------
__global__ __launch_bounds__(256) void ln_kernel(const float* __restrict__ x,
                                                 const float* __restrict__ g,
                                                 const float* __restrict__ b,
                                                 __bf16* __restrict__ out) {
  int row = blockIdx.x;
  const float* xr = x + (size_t)row * D_;
  __bf16* outr = out + (size_t)row * D_;
  int tid = threadIdx.x;

  float4 v = ((const float4*)xr)[tid];
  float s = v.x + v.y + v.z + v.w;
  float ss = v.x * v.x + v.y * v.y + v.z * v.z + v.w * v.w;

  #pragma unroll
  for (int m = 1; m < 64; m <<= 1) {
    s += __shfl_xor(s, m);
    ss += __shfl_xor(ss, m);
  }
  __shared__ float red[10];
  int wid = tid >> 6;
  if ((tid & 63) == 0) { red[wid] = s; red[4 + wid] = ss; }
  __syncthreads();
  if (tid == 0) {
    float ts = red[0] + red[1] + red[2] + red[3];
    float tss = red[4] + red[5] + red[6] + red[7];
    float mu = ts * (1.0f / D_);
    float var = tss * (1.0f / D_) - mu * mu;
    red[8] = mu;
    red[9] = rsqrtf(var + 1e-5f);
  }
  __syncthreads();
  float mu = red[8], rstd = red[9];
  float4 gv = ((const float4*)g)[tid];
  float4 bv = ((const float4*)b)[tid];
  bf16x4 o;
  o[0] = (__bf16)((v.x - mu) * rstd * gv.x + bv.x);
  o[1] = (__bf16)((v.y - mu) * rstd * gv.y + bv.y);
  o[2] = (__bf16)((v.z - mu) * rstd * gv.z + bv.z);
  o[3] = (__bf16)((v.w - mu) * rstd * gv.w + bv.w);
  *(bf16x4*)(outr + tid * 4) = o;
}

// ---------------- Weight transpose+convert: fp32 [1024][1024] -> bf16 [N][K] ----------------
__global__ __launch_bounds__(256) void transpose_w(const float* __restrict__ in,
                                                   __bf16* __restrict__ out) {
  __shared__ float t[64][65];
  const int n0 = blockIdx.x * 64, k0 = blockIdx.y * 64;
  const int tid = threadIdx.x;
  const int r = tid >> 4, c4 = (tid & 15) * 4;
  #pragma unroll
  for (int i = 0; i < 4; ++i) {
    float4 v = *(const float4*)&in[(size_t)(k0 + i * 16 + r) * D_ + n0 + c4];
    t[i * 16 + r][c4 + 0] = v.x;
    t[i * 16 + r][c4 + 1] = v.y;
    t[i * 16 + r][c4 + 2] = v.z;
    t[i * 16 + r][c4 + 3] = v.w;
  }
  __syncthreads();
  #pragma unroll
  for (int i = 0; i < 4; ++i) {
    bf16x4 o;
    #pragma unroll
    for (int j = 0; j < 4; ++j) o[j] = (__bf16)t[c4 + j][i * 16 + r];
    *(bf16x4*)&out[(size_t)(n0 + i * 16 + r) * D_ + k0 + c4] = o;
  }
}

// ---- QKV weights: [H][D][HD] fp32 (x3) -> bf16 rows n = which*1024 + h*64 + e, col k = d ----
__global__ __launch_bounds__(256) void transpose_qkv(const float* __restrict__ Wq,
                                                     const float* __restrict__ Wk,
                                                     const float* __restrict__ Wv,
                                                     __bf16* __restrict__ out) {
  __shared__ float t[64][65];
  const int d0 = blockIdx.x * 64;
  const int h = blockIdx.y;
  const int which = blockIdx.z;
  const float* in = (which == 0 ? Wq : which == 1 ? Wk : Wv) + (size_t)h * D_ * HD_;
  const int tid = threadIdx.x;
  const int r = tid >> 4, c4 = (tid & 15) * 4;
  #pragma unroll
  for (int i = 0; i < 4; ++i) {
    float4 v = *(const float4*)&in[(size_t)(d0 + i * 16 + r) * HD_ + c4];
    t[i * 16 + r][c4 + 0] = v.x;
    t[i * 16 + r][c4 + 1] = v.y;
    t[i * 16 + r][c4 + 2] = v.z;
    t[i * 16 + r][c4 + 3] = v.w;
  }
  __syncthreads();
  #pragma unroll
  for (int i = 0; i < 4; ++i) {
    bf16x4 o;
    #pragma unroll
    for (int j = 0; j < 4; ++j) o[j] = (__bf16)t[c4 + j][i * 16 + r];
    *(bf16x4*)&out[(size_t)(which * 1024 + h * 64 + i * 16 + r) * D_ + d0 + c4] = o;
  }
}

// ---------------- bf16 MFMA GEMM, m97 structure: 128x128 tile, BK=64 ----------------
#define MODE_QKV 0
#define MODE_PROJ 1
#define MODE_FF1 2
#define MODE_FF2 3

template <int MODE>
__global__ __launch_bounds__(256) void gemm_mfma(const __bf16* __restrict__ A,
                                                 const __bf16* __restrict__ Bt,
                                                 const float* __restrict__ bias,
                                                 const float* __restrict__ resid,
                                                 float* __restrict__ outf,
                                                 __bf16* __restrict__ outb,
                                                 int M, int N, int K) {
  __shared__ __align__(16) __bf16 As[128 * 64];
  __shared__ __align__(16) __bf16 Bs[128 * 64];
  const int tid = threadIdx.x;
  const int m0 = blockIdx.y * 128, n0 = blockIdx.x * 128;
  const int w = tid >> 6, l = tid & 63, lr = l & 15, lg = l >> 4;
  const int wm = (w >> 1) * 64, wn = (w & 1) * 64;

  f32x4 acc[4][4] = {};

  for (int k0 = 0; k0 < K; k0 += 64) {
    __syncthreads();
    #pragma unroll
    for (int i = 0; i < 4; ++i) {
      int e = i * 256 + tid;
      gld_lds16(A + (size_t)(m0 + (e >> 3)) * K + k0 + (e & 7) * 8, &As[e * 8]);
    }
    #pragma unroll
    for (int i = 0; i < 4; ++i) {
      int e = i * 256 + tid;
      gld_lds16(Bt + (size_t)(n0 + (e >> 3)) * K + k0 + (e & 7) * 8, &Bs[e * 8]);
    }
    asm volatile("s_waitcnt vmcnt(0)");
    __syncthreads();

    #pragma unroll
    for (int kk = 0; kk < 2; ++kk) {
      bf16x8 af[4], bfr[4];
      #pragma unroll
      for (int i = 0; i < 4; ++i)
        af[i] = *(const bf16x8*)&As[(wm + i * 16 + lr) * 64 + kk * 32 + lg * 8];
      #pragma unroll
      for (int j = 0; j < 4; ++j)
        bfr[j] = *(const bf16x8*)&Bs[(wn + j * 16 + lr) * 64 + kk * 32 + lg * 8];
      #pragma unroll
      for (int i = 0; i < 4; ++i)
        #pragma unroll
        for (int j = 0; j < 4; ++j)
          acc[i][j] = __builtin_amdgcn_mfma_f32_16x16x32_bf16(af[i], bfr[j], acc[i][j], 0, 0, 0);
    }
  }

  #pragma unroll
  for (int i = 0; i < 4; ++i) {
    #pragma unroll
    for (int j = 0; j < 4; ++j) {
      #pragma unroll
      for (int r = 0; r < 4; ++r) {
        int m = m0 + wm + i * 16 + 4 * lg + r;
        int n = n0 + wn + j * 16 + lr;
        float val = acc[i][j][r];
        if (MODE == MODE_QKV) {
          int b = m >> 10, s = m & 1023;
          int which = n >> 10, hh = (n >> 6) & 15, e = n & 63;
          outb[(size_t)which * 8388608 + ((size_t)(b * 16 + hh) * 1024 + s) * 64 + e] =
              (__bf16)val;
        } else if (MODE == MODE_PROJ) {
          size_t idx = (size_t)m * 1024 + n;
          outf[idx] = resid[idx] + val + bias[n];
        } else if (MODE == MODE_FF1) {
          val += bias[n];
          outb[(size_t)m * 1024 + n] =
              (__bf16)(0.5f * val * (1.0f + erff(val * 0.70710678118654752f)));
        } else {
          size_t idx = (size_t)m * 1024 + n;
          outf[idx] = outf[idx] + val + bias[n];
        }
      }
    }
  }
}

// ---------------- Flash attention v2: swapped QK^T, lane-local softmax ----------------
// Block = 256 thr (4 waves); wave owns 16 q-rows; KV tiles of 64.
// S^T = mfma(K,Q): lane (lr,lg) holds S[t=16g+4lg+r][q=lr] -> softmax in-lane + 2 shfl.
// V^T staged in LDS with permuted t-columns c(t)=[t5 t3 t2 t4 t1 t0] so that the PV
// A-frag is exactly the lane's own 16 p-values: af[kk][j] = p[2kk+(j>>2)][j&3].
__global__ __launch_bounds__(256) void fattn(const __bf16* __restrict__ q,
                                             const __bf16* __restrict__ k,
                                             const __bf16* __restrict__ v,
                                             __bf16* __restrict__ outC) {
  __shared__ __align__(16) __bf16 Vp[64][72];   // [e][c] permuted V^T, pad 72

  const int bh = blockIdx.x >> 4;
  const int qt = blockIdx.x & 15;
  const int tid = threadIdx.x;
  const int w = tid >> 6, l = tid & 63;
  const int lr = l & 15, lg = l >> 4;

  const size_t base = (size_t)bh * S_ * HD_;
  const int qrow0 = qt * 64 + w * 16;

  // Q B-frags, pre-scaled by 1/8 (exact in bf16)
  bf16x8 qf0, qf1;
  {
    const __bf16* qp = q + base + (size_t)(qrow0 + lr) * HD_ + lg * 8;
    qf0 = *(const bf16x8*)(qp);
    qf1 = *(const bf16x8*)(qp + 32);
    #pragma unroll
    for (int i = 0; i < 8; ++i) qf0[i] = (__bf16)((float)qf0[i] * 0.125f);
    #pragma unroll
    for (int i = 0; i < 8; ++i) qf1[i] = (__bf16)((float)qf1[i] * 0.125f);
  }

  f32x4 oacc[4] = {{0,0,0,0},{0,0,0,0},{0,0,0,0},{0,0,0,0}};
  float m_run = -1e30f, l_run = 0.f;

  // V staging: thread handles source row t = tid&63, e-chunk = tid>>6
  const int vt = tid & 63;
  const int vw = tid >> 6;
  const int vc = ((vt & 0x20)) + ((vt & 0xC) << 1) + ((vt & 0x10) >> 2) + (vt & 3);

  for (int t0 = 0; t0 < S_; t0 += 64) {
    __syncthreads();  // all waves done reading previous Vp
    {
      const __bf16* vp = v + base + (size_t)(t0 + vt) * HD_ + vw * 16;
      bf16x8 v0 = *(const bf16x8*)vp;
      bf16x8 v1 = *(const bf16x8*)(vp + 8);
      #pragma unroll
      for (int i = 0; i < 8; ++i) Vp[vw * 16 + i][vc] = v0[i];
      #pragma unroll
      for (int i = 0; i < 8; ++i) Vp[vw * 16 + 8 + i][vc] = v1[i];
    }
    __syncthreads();

    // ---- S^T = mfma(K, Q): sacc[g][r] = S[t=16g+4lg+r][q=lr] (pre-scaled) ----
    f32x4 sacc[4];
    const __bf16* kp = k + base + (size_t)(t0 + lr) * HD_ + lg * 8;
    #pragma unroll
    for (int g = 0; g < 4; ++g) {
      bf16x8 kf0 = *(const bf16x8*)(kp + (size_t)g * 16 * HD_);
      bf16x8 kf1 = *(const bf16x8*)(kp + (size_t)g * 16 * HD_ + 32);
      f32x4 z = {0.f, 0.f, 0.f, 0.f};
      z = __builtin_amdgcn_mfma_f32_16x16x32_bf16(kf0, qf0, z, 0, 0, 0);
      sacc[g] = __builtin_amdgcn_mfma_f32_16x16x32_bf16(kf1, qf1, z, 0, 0, 0);
    }

    // ---- online softmax, lane-local over 16 t-values + 2 shfl (lg dim) ----
    float tm = sacc[0][0];
    #pragma unroll
    for (int g = 0; g < 4; ++g)
      #pragma unroll
      for (int r = 0; r < 4; ++r) tm = fmaxf(tm, sacc[g][r]);
    tm = fmaxf(tm, __shfl_xor(tm, 16));
    tm = fmaxf(tm, __shfl_xor(tm, 32));

    if (!__all(tm - m_run <= 8.0f)) {  // defer-max (T13): rescale only on real growth
      float mn = fmaxf(m_run, tm);
      float corr = __expf(m_run - mn);
      m_run = mn;
      l_run *= corr;
      #pragma unroll
      for (int r = 0; r < 4; ++r) {
        float cq = __shfl(corr, 4 * lg + r);
        #pragma unroll
        for (int g = 0; g < 4; ++g) oacc[g][r] *= cq;
      }
    }

    float p[4][4];
    float ps = 0.f;
    #pragma unroll
    for (int g = 0; g < 4; ++g)
      #pragma unroll
      for (int r = 0; r < 4; ++r) {
        p[g][r] = __expf(sacc[g][r] - m_run);
        ps += p[g][r];
      }
    ps += __shfl_xor(ps, 16);
    ps += __shfl_xor(ps, 32);
    l_run += ps;

    // ---- PV: A-frag = own p-values (permutation-matched to Vp layout) ----
    bf16x8 af0, af1;
    #pragma unroll
    for (int j = 0; j < 8; ++j) {
      af0[j] = (__bf16)p[j >> 2][j & 3];
      af1[j] = (__bf16)p[2 + (j >> 2)][j & 3];
    }
    #pragma unroll
    for (int g = 0; g < 4; ++g) {
      bf16x8 vf0 = *(const bf16x8*)&Vp[16 * g + lr][lg * 8];
      bf16x8 vf1 = *(const bf16x8*)&Vp[16 * g + lr][32 + lg * 8];
      oacc[g] = __builtin_amdgcn_mfma_f32_16x16x32_bf16(af0, vf0, oacc[g], 0, 0, 0);
      oacc[g] = __builtin_amdgcn_mfma_f32_16x16x32_bf16(af1, vf1, oacc[g], 0, 0, 0);
    }
  }

  // ---- epilogue: O[q=4lg+r][e=16g+lr] /= l_run[q]; scatter to concat layout ----
  const int b = bh >> 4, hh = bh & 15;
  #pragma unroll
  for (int r = 0; r < 4; ++r) {
    float linv = 1.0f / __shfl(l_run, 4 * lg + r);
    int srow = qrow0 + 4 * lg + r;
    __bf16* op = outC + ((size_t)(b * S_ + srow)) * D_ + hh * HD_;
    #pragma unroll
    for (int g = 0; g < 4; ++g) op[16 * g + lr] = (__bf16)(oacc[g][r] * linv);
  }
}

extern "C" void kernel_launch(void* const* d_in, const int* in_sizes, int n_in,
                              void* d_out, int out_size, void* d_ws, size_t ws_size,
                              hipStream_t stream) {
  const float* x   = (const float*)d_in[0];
  const float* Wq  = (const float*)d_in[1];
  const float* Wk  = (const float*)d_in[2];
  const float* Wv  = (const float*)d_in[3];
  const float* Wo  = (const float*)d_in[4];
  const float* bo  = (const float*)d_in[5];
  const float* W1  = (const float*)d_in[6];
  const float* b1  = (const float*)d_in[7];
  const float* W2  = (const float*)d_in[8];
  const float* b2  = (const float*)d_in[9];
  const float* g1  = (const float*)d_in[10];
  const float* bl1 = (const float*)d_in[11];
  const float* g2  = (const float*)d_in[12];
  const float* bl2 = (const float*)d_in[13];
  float* out = (float*)d_out;

  const size_t MN = (size_t)B_ * S_ * D_;  // 8388608
  __bf16* h     = (__bf16*)d_ws;
  __bf16* wt    = h + MN;
  __bf16* qkv   = wt + (size_t)6144 * 1024;
  __bf16* attnC = qkv + 3 * MN;
  __bf16* ff1   = attnC + MN;

  __bf16* wqkv_t = wt;
  __bf16* wo_t   = wt + (size_t)3072 * 1024;
  __bf16* w1_t   = wt + (size_t)4096 * 1024;
  __bf16* w2_t   = wt + (size_t)5120 * 1024;

  const int rows = B_ * S_;  // 8192

  ln_kernel<<<rows, 256, 0, stream>>>(x, g1, bl1, h);
  transpose_qkv<<<dim3(16, 16, 3), 256, 0, stream>>>(Wq, Wk, Wv, wqkv_t);
  transpose_w<<<dim3(16, 16), 256, 0, stream>>>(Wo, wo_t);
  transpose_w<<<dim3(16, 16), 256, 0, stream>>>(W1, w1_t);
  transpose_w<<<dim3(16, 16), 256, 0, stream>>>(W2, w2_t);

  gemm_mfma<MODE_QKV><<<dim3(24, 64), 256, 0, stream>>>(
      h, wqkv_t, nullptr, nullptr, nullptr, qkv, rows, 3072, D_);
  fattn<<<B_ * H_ * (S_ / 64), 256, 0, stream>>>(qkv, qkv + MN, qkv + 2 * MN, attnC);
  gemm_mfma<MODE_PROJ><<<dim3(8, 64), 256, 0, stream>>>(
      attnC, wo_t, bo, x, out, nullptr, rows, D_, D_);
  ln_kernel<<<rows, 256, 0, stream>>>(out, g2, bl2, h);
  gemm_mfma<MODE_FF1><<<dim3(8, 64), 256, 0, stream>>>(
      h, w1_t, b1, nullptr, nullptr, ff1, rows, D_, D_);
  gemm_mfma<MODE_FF2><<<dim3(8, 64), 256, 0, stream>>>(
      ff1, w2_t, b2, nullptr, out, nullptr, rows, D_, D_);
}

// Round 5
// 294.782 us; speedup vs baseline: 1.2817x; 1.2817x over previous
//
#include <hip/hip_runtime.h>
#include <hip/hip_bf16.h>
#include <math.h>

#define B_ 8
#define S_ 1024
#define D_ 1024
#define H_ 16
#define HD_ 64

typedef __bf16 bf16x8 __attribute__((ext_vector_type(8)));
typedef __bf16 bf16x4 __attribute__((ext_vector_type(4)));
typedef float f32x4 __attribute__((ext_vector_type(4)));

__device__ __forceinline__ void gld_lds16(const __bf16* g, __bf16* l) {
  __builtin_amdgcn_global_load_lds(
      (const __attribute__((address_space(1))) void*)g,
      (__attribute__((address_space(3))) void*)l, 16, 0, 0);
}

// ---------------- LayerNorm: fp32 in, bf16 out ----------------
__global__ __launch_bounds__(256) void ln_kernel(const float* __restrict__ x,
                                                 const float* __restrict__ g,
                                                 const float* __restrict__ b,
                                                 __bf16* __restrict__ out) {
  int row = blockIdx.x;
  const float* xr = x + (size_t)row * D_;
  __bf16* outr = out + (size_t)row * D_;
  int tid = threadIdx.x;

  float4 v = ((const float4*)xr)[tid];
  float s = v.x + v.y + v.z + v.w;
  float ss = v.x * v.x + v.y * v.y + v.z * v.z + v.w * v.w;

  #pragma unroll
  for (int m = 1; m < 64; m <<= 1) {
    s += __shfl_xor(s, m);
    ss += __shfl_xor(ss, m);
  }
  __shared__ float red[10];
  int wid = tid >> 6;
  if ((tid & 63) == 0) { red[wid] = s; red[4 + wid] = ss; }
  __syncthreads();
  if (tid == 0) {
    float ts = red[0] + red[1] + red[2] + red[3];
    float tss = red[4] + red[5] + red[6] + red[7];
    float mu = ts * (1.0f / D_);
    float var = tss * (1.0f / D_) - mu * mu;
    red[8] = mu;
    red[9] = rsqrtf(var + 1e-5f);
  }
  __syncthreads();
  float mu = red[8], rstd = red[9];
  float4 gv = ((const float4*)g)[tid];
  float4 bv = ((const float4*)b)[tid];
  bf16x4 o;
  o[0] = (__bf16)((v.x - mu) * rstd * gv.x + bv.x);
  o[1] = (__bf16)((v.y - mu) * rstd * gv.y + bv.y);
  o[2] = (__bf16)((v.z - mu) * rstd * gv.z + bv.z);
  o[3] = (__bf16)((v.w - mu) * rstd * gv.w + bv.w);
  *(bf16x4*)(outr + tid * 4) = o;
}

// ---------------- Weight transpose+convert: fp32 [1024][1024] -> bf16 [N][K] ----------------
__global__ __launch_bounds__(256) void transpose_w(const float* __restrict__ in,
                                                   __bf16* __restrict__ out) {
  __shared__ float t[64][65];
  const int n0 = blockIdx.x * 64, k0 = blockIdx.y * 64;
  const int tid = threadIdx.x;
  const int r = tid >> 4, c4 = (tid & 15) * 4;
  #pragma unroll
  for (int i = 0; i < 4; ++i) {
    float4 v = *(const float4*)&in[(size_t)(k0 + i * 16 + r) * D_ + n0 + c4];
    t[i * 16 + r][c4 + 0] = v.x;
    t[i * 16 + r][c4 + 1] = v.y;
    t[i * 16 + r][c4 + 2] = v.z;
    t[i * 16 + r][c4 + 3] = v.w;
  }
  __syncthreads();
  #pragma unroll
  for (int i = 0; i < 4; ++i) {
    bf16x4 o;
    #pragma unroll
    for (int j = 0; j < 4; ++j) o[j] = (__bf16)t[c4 + j][i * 16 + r];
    *(bf16x4*)&out[(size_t)(n0 + i * 16 + r) * D_ + k0 + c4] = o;
  }
}

// ---- QKV weights: [H][D][HD] fp32 (x3) -> bf16 rows n = which*1024 + h*64 + e, col k = d ----
__global__ __launch_bounds__(256) void transpose_qkv(const float* __restrict__ Wq,
                                                     const float* __restrict__ Wk,
                                                     const float* __restrict__ Wv,
                                                     __bf16* __restrict__ out) {
  __shared__ float t[64][65];
  const int d0 = blockIdx.x * 64;
  const int h = blockIdx.y;
  const int which = blockIdx.z;
  const float* in = (which == 0 ? Wq : which == 1 ? Wk : Wv) + (size_t)h * D_ * HD_;
  const int tid = threadIdx.x;
  const int r = tid >> 4, c4 = (tid & 15) * 4;
  #pragma unroll
  for (int i = 0; i < 4; ++i) {
    float4 v = *(const float4*)&in[(size_t)(d0 + i * 16 + r) * HD_ + c4];
    t[i * 16 + r][c4 + 0] = v.x;
    t[i * 16 + r][c4 + 1] = v.y;
    t[i * 16 + r][c4 + 2] = v.z;
    t[i * 16 + r][c4 + 3] = v.w;
  }
  __syncthreads();
  #pragma unroll
  for (int i = 0; i < 4; ++i) {
    bf16x4 o;
    #pragma unroll
    for (int j = 0; j < 4; ++j) o[j] = (__bf16)t[c4 + j][i * 16 + r];
    *(bf16x4*)&out[(size_t)(which * 1024 + h * 64 + i * 16 + r) * D_ + d0 + c4] = o;
  }
}

// ---------------- bf16 MFMA GEMM, m97 structure: 128x128 tile, BK=64 ----------------
#define MODE_QKV 0
#define MODE_PROJ 1
#define MODE_FF1 2
#define MODE_FF2 3

template <int MODE>
__global__ __launch_bounds__(256) void gemm_mfma(const __bf16* __restrict__ A,
                                                 const __bf16* __restrict__ Bt,
                                                 const float* __restrict__ bias,
                                                 const float* __restrict__ resid,
                                                 float* __restrict__ outf,
                                                 __bf16* __restrict__ outb,
                                                 int M, int N, int K) {
  __shared__ __align__(16) __bf16 As[128 * 64];
  __shared__ __align__(16) __bf16 Bs[128 * 64];
  const int tid = threadIdx.x;
  const int m0 = blockIdx.y * 128, n0 = blockIdx.x * 128;
  const int w = tid >> 6, l = tid & 63, lr = l & 15, lg = l >> 4;
  const int wm = (w >> 1) * 64, wn = (w & 1) * 64;

  f32x4 acc[4][4] = {};

  for (int k0 = 0; k0 < K; k0 += 64) {
    __syncthreads();
    #pragma unroll
    for (int i = 0; i < 4; ++i) {
      int e = i * 256 + tid;
      gld_lds16(A + (size_t)(m0 + (e >> 3)) * K + k0 + (e & 7) * 8, &As[e * 8]);
    }
    #pragma unroll
    for (int i = 0; i < 4; ++i) {
      int e = i * 256 + tid;
      gld_lds16(Bt + (size_t)(n0 + (e >> 3)) * K + k0 + (e & 7) * 8, &Bs[e * 8]);
    }
    asm volatile("s_waitcnt vmcnt(0)");
    __syncthreads();

    #pragma unroll
    for (int kk = 0; kk < 2; ++kk) {
      bf16x8 af[4], bfr[4];
      #pragma unroll
      for (int i = 0; i < 4; ++i)
        af[i] = *(const bf16x8*)&As[(wm + i * 16 + lr) * 64 + kk * 32 + lg * 8];
      #pragma unroll
      for (int j = 0; j < 4; ++j)
        bfr[j] = *(const bf16x8*)&Bs[(wn + j * 16 + lr) * 64 + kk * 32 + lg * 8];
      #pragma unroll
      for (int i = 0; i < 4; ++i)
        #pragma unroll
        for (int j = 0; j < 4; ++j)
          acc[i][j] = __builtin_amdgcn_mfma_f32_16x16x32_bf16(af[i], bfr[j], acc[i][j], 0, 0, 0);
    }
  }

  #pragma unroll
  for (int i = 0; i < 4; ++i) {
    #pragma unroll
    for (int j = 0; j < 4; ++j) {
      #pragma unroll
      for (int r = 0; r < 4; ++r) {
        int m = m0 + wm + i * 16 + 4 * lg + r;
        int n = n0 + wn + j * 16 + lr;
        float val = acc[i][j][r];
        if (MODE == MODE_QKV) {
          int b = m >> 10, s = m & 1023;
          int which = n >> 10, hh = (n >> 6) & 15, e = n & 63;
          outb[(size_t)which * 8388608 + ((size_t)(b * 16 + hh) * 1024 + s) * 64 + e] =
              (__bf16)val;
        } else if (MODE == MODE_PROJ) {
          size_t idx = (size_t)m * 1024 + n;
          outf[idx] = resid[idx] + val + bias[n];
        } else if (MODE == MODE_FF1) {
          val += bias[n];
          outb[(size_t)m * 1024 + n] =
              (__bf16)(0.5f * val * (1.0f + erff(val * 0.70710678118654752f)));
        } else {
          size_t idx = (size_t)m * 1024 + n;
          outf[idx] = outf[idx] + val + bias[n];
        }
      }
    }
  }
}

// ---------------- Flash attention v3: pipelined (K gld_lds dbuf + V async-split dbuf) ----------
// Block = 256 thr (4 waves); wave owns 16 q-rows; KV tiles of 64; 16 tiles.
// S^T = mfma(K,Q): lane (lr,lg) holds S[t=16g+4lg+r][q=lr] -> softmax lane-local + 2 shfl.
// K LDS layout: [buf][kc=8][row=64] 16B chunks -> QK ds_read_b128 at bank 4*lr%32 (2-way, free).
// V^T in LDS with permuted t-columns c(t)=[t5 t3 t2 t4 t1 t0]; PV A-frag = own p-values.
__global__ __launch_bounds__(256) void fattn(const __bf16* __restrict__ q,
                                             const __bf16* __restrict__ k,
                                             const __bf16* __restrict__ v,
                                             __bf16* __restrict__ outC) {
  __shared__ __align__(16) __bf16 Klds[2][8 * 64 * 8];  // [buf][kc][row][8]
  __shared__ __align__(16) __bf16 Vp[2][64][72];        // [buf][e][c] permuted V^T

  const int bh = blockIdx.x >> 4;
  const int qt = blockIdx.x & 15;
  const int tid = threadIdx.x;
  const int w = tid >> 6, l = tid & 63;
  const int lr = l & 15, lg = l >> 4;

  const size_t base = (size_t)bh * S_ * HD_;
  const int qrow0 = qt * 64 + w * 16;
  const __bf16* kg = k + base;
  const __bf16* vg = v + base;

  // Q B-frags, pre-scaled by 1/8 (exact in bf16)
  bf16x8 qf0, qf1;
  {
    const __bf16* qp = q + base + (size_t)(qrow0 + lr) * HD_ + lg * 8;
    qf0 = *(const bf16x8*)(qp);
    qf1 = *(const bf16x8*)(qp + 32);
    #pragma unroll
    for (int i = 0; i < 8; ++i) qf0[i] = (__bf16)((float)qf0[i] * 0.125f);
    #pragma unroll
    for (int i = 0; i < 8; ++i) qf1[i] = (__bf16)((float)qf1[i] * 0.125f);
  }

  f32x4 oacc[4] = {{0,0,0,0},{0,0,0,0},{0,0,0,0},{0,0,0,0}};
  float m_run = -1e30f, l_run = 0.f;

  // V staging geometry (permuted column for source row t = l)
  const int vc = (l & 0x20) + ((l & 0xC) << 1) + ((l & 0x10) >> 2) + (l & 3);
  // K staging: issue qk2 = 2w+i covers kchunk qk2, row = l
  const int kq0 = 2 * w, kq1 = 2 * w + 1;

  // ---- prologue: stage K(0), load+write V(0), load V(1) ----
  gld_lds16(kg + (size_t)l * HD_ + kq0 * 8, &Klds[0][(kq0 * 64 + l) * 8]);
  gld_lds16(kg + (size_t)l * HD_ + kq1 * 8, &Klds[0][(kq1 * 64 + l) * 8]);
  bf16x8 vr0, vr1;
  {
    const __bf16* vp = vg + (size_t)l * HD_ + w * 16;
    vr0 = *(const bf16x8*)vp;
    vr1 = *(const bf16x8*)(vp + 8);
    #pragma unroll
    for (int i = 0; i < 8; ++i) Vp[0][w * 16 + i][vc] = vr0[i];
    #pragma unroll
    for (int i = 0; i < 8; ++i) Vp[0][w * 16 + 8 + i][vc] = vr1[i];
    const __bf16* vp1 = vg + (size_t)(64 + l) * HD_ + w * 16;
    vr0 = *(const bf16x8*)vp1;
    vr1 = *(const bf16x8*)(vp1 + 8);
  }
  asm volatile("s_waitcnt vmcnt(0)");
  __syncthreads();

  int cur = 0;
  for (int t = 0; t < 16; ++t) {
    // ---- stage K(t+1) into Klds[cur^1] (clamped; last-iter write is unread) ----
    {
      int tn = (t < 15) ? (t + 1) : 15;
      const __bf16* ks = kg + ((size_t)tn * 64 + l) * HD_;
      gld_lds16(ks + kq0 * 8, &Klds[cur ^ 1][(kq0 * 64 + l) * 8]);
      gld_lds16(ks + kq1 * 8, &Klds[cur ^ 1][(kq1 * 64 + l) * 8]);
    }

    // ---- QK: S^T = mfma(K, Q) from Klds[cur] ----
    f32x4 sacc[4];
    const __bf16* kb = &Klds[cur][0];
    __builtin_amdgcn_s_setprio(1);
    #pragma unroll
    for (int g = 0; g < 4; ++g) {
      bf16x8 kf0 = *(const bf16x8*)&kb[(lg * 64 + 16 * g + lr) * 8];
      bf16x8 kf1 = *(const bf16x8*)&kb[((lg + 4) * 64 + 16 * g + lr) * 8];
      f32x4 z = {0.f, 0.f, 0.f, 0.f};
      z = __builtin_amdgcn_mfma_f32_16x16x32_bf16(kf0, qf0, z, 0, 0, 0);
      sacc[g] = __builtin_amdgcn_mfma_f32_16x16x32_bf16(kf1, qf1, z, 0, 0, 0);
    }
    __builtin_amdgcn_s_setprio(0);

    // ---- online softmax (lane-local 16 + 2 shfl) ----
    float tm = sacc[0][0];
    #pragma unroll
    for (int g = 0; g < 4; ++g)
      #pragma unroll
      for (int r = 0; r < 4; ++r) tm = fmaxf(tm, sacc[g][r]);
    tm = fmaxf(tm, __shfl_xor(tm, 16));
    tm = fmaxf(tm, __shfl_xor(tm, 32));

    if (!__all(tm - m_run <= 8.0f)) {
      float mn = fmaxf(m_run, tm);
      float corr = __expf(m_run - mn);
      m_run = mn;
      l_run *= corr;
      #pragma unroll
      for (int r = 0; r < 4; ++r) {
        float cq = __shfl(corr, 4 * lg + r);
        #pragma unroll
        for (int g = 0; g < 4; ++g) oacc[g][r] *= cq;
      }
    }

    float p[4][4];
    float ps = 0.f;
    #pragma unroll
    for (int g = 0; g < 4; ++g)
      #pragma unroll
      for (int r = 0; r < 4; ++r) {
        p[g][r] = __expf(sacc[g][r] - m_run);
        ps += p[g][r];
      }
    ps += __shfl_xor(ps, 16);
    ps += __shfl_xor(ps, 32);
    l_run += ps;

    // ---- write V(t+1) regs -> Vp[cur^1] (loads issued one iter ago: latency hidden) ----
    #pragma unroll
    for (int i = 0; i < 8; ++i) Vp[cur ^ 1][w * 16 + i][vc] = vr0[i];
    #pragma unroll
    for (int i = 0; i < 8; ++i) Vp[cur ^ 1][w * 16 + 8 + i][vc] = vr1[i];

    // ---- issue V(t+2) global loads (consumed next iteration) ----
    {
      int tnn = (t < 14) ? (t + 2) : 15;
      const __bf16* vp = vg + ((size_t)tnn * 64 + l) * HD_ + w * 16;
      vr0 = *(const bf16x8*)vp;
      vr1 = *(const bf16x8*)(vp + 8);
    }

    // ---- PV: A-frag = own p-values; B from Vp[cur] ----
    bf16x8 af0, af1;
    #pragma unroll
    for (int j = 0; j < 8; ++j) {
      af0[j] = (__bf16)p[j >> 2][j & 3];
      af1[j] = (__bf16)p[2 + (j >> 2)][j & 3];
    }
    __builtin_amdgcn_s_setprio(1);
    #pragma unroll
    for (int g = 0; g < 4; ++g) {
      bf16x8 vf0 = *(const bf16x8*)&Vp[cur][16 * g + lr][lg * 8];
      bf16x8 vf1 = *(const bf16x8*)&Vp[cur][16 * g + lr][32 + lg * 8];
      oacc[g] = __builtin_amdgcn_mfma_f32_16x16x32_bf16(af0, vf0, oacc[g], 0, 0, 0);
      oacc[g] = __builtin_amdgcn_mfma_f32_16x16x32_bf16(af1, vf1, oacc[g], 0, 0, 0);
    }
    __builtin_amdgcn_s_setprio(0);

    asm volatile("s_waitcnt vmcnt(0)");  // K(t+1) gld_lds drained (sync would anyway)
    __syncthreads();
    cur ^= 1;
  }

  // ---- epilogue: O[q=4lg+r][e=16g+lr] /= l_run[q]; scatter to concat layout ----
  const int b = bh >> 4, hh = bh & 15;
  #pragma unroll
  for (int r = 0; r < 4; ++r) {
    float linv = 1.0f / __shfl(l_run, 4 * lg + r);
    int srow = qrow0 + 4 * lg + r;
    __bf16* op = outC + ((size_t)(b * S_ + srow)) * D_ + hh * HD_;
    #pragma unroll
    for (int g = 0; g < 4; ++g) op[16 * g + lr] = (__bf16)(oacc[g][r] * linv);
  }
}

extern "C" void kernel_launch(void* const* d_in, const int* in_sizes, int n_in,
                              void* d_out, int out_size, void* d_ws, size_t ws_size,
                              hipStream_t stream) {
  const float* x   = (const float*)d_in[0];
  const float* Wq  = (const float*)d_in[1];
  const float* Wk  = (const float*)d_in[2];
  const float* Wv  = (const float*)d_in[3];
  const float* Wo  = (const float*)d_in[4];
  const float* bo  = (const float*)d_in[5];
  const float* W1  = (const float*)d_in[6];
  const float* b1  = (const float*)d_in[7];
  const float* W2  = (const float*)d_in[8];
  const float* b2  = (const float*)d_in[9];
  const float* g1  = (const float*)d_in[10];
  const float* bl1 = (const float*)d_in[11];
  const float* g2  = (const float*)d_in[12];
  const float* bl2 = (const float*)d_in[13];
  float* out = (float*)d_out;

  const size_t MN = (size_t)B_ * S_ * D_;  // 8388608
  __bf16* h     = (__bf16*)d_ws;
  __bf16* wt    = h + MN;
  __bf16* qkv   = wt + (size_t)6144 * 1024;
  __bf16* attnC = qkv + 3 * MN;
  __bf16* ff1   = attnC + MN;

  __bf16* wqkv_t = wt;
  __bf16* wo_t   = wt + (size_t)3072 * 1024;
  __bf16* w1_t   = wt + (size_t)4096 * 1024;
  __bf16* w2_t   = wt + (size_t)5120 * 1024;

  const int rows = B_ * S_;  // 8192

  ln_kernel<<<rows, 256, 0, stream>>>(x, g1, bl1, h);
  transpose_qkv<<<dim3(16, 16, 3), 256, 0, stream>>>(Wq, Wk, Wv, wqkv_t);
  transpose_w<<<dim3(16, 16), 256, 0, stream>>>(Wo, wo_t);
  transpose_w<<<dim3(16, 16), 256, 0, stream>>>(W1, w1_t);
  transpose_w<<<dim3(16, 16), 256, 0, stream>>>(W2, w2_t);

  gemm_mfma<MODE_QKV><<<dim3(24, 64), 256, 0, stream>>>(
      h, wqkv_t, nullptr, nullptr, nullptr, qkv, rows, 3072, D_);
  fattn<<<B_ * H_ * (S_ / 64), 256, 0, stream>>>(qkv, qkv + MN, qkv + 2 * MN, attnC);
  gemm_mfma<MODE_PROJ><<<dim3(8, 64), 256, 0, stream>>>(
      attnC, wo_t, bo, x, out, nullptr, rows, D_, D_);
  ln_kernel<<<rows, 256, 0, stream>>>(out, g2, bl2, h);
  gemm_mfma<MODE_FF1><<<dim3(8, 64), 256, 0, stream>>>(
      h, w1_t, b1, nullptr, nullptr, ff1, rows, D_, D_);
  gemm_mfma<MODE_FF2><<<dim3(8, 64), 256, 0, stream>>>(
      ff1, w2_t, b2, nullptr, out, nullptr, rows, D_, D_);
}

// Round 6
// 254.435 us; speedup vs baseline: 1.4849x; 1.1586x over previous
//
#include <hip/hip_runtime.h>
#include <hip/hip_bf16.h>
#include <math.h>

#define B_ 8
#define S_ 1024
#define D_ 1024
#define H_ 16
#define HD_ 64

typedef __bf16 bf16x8 __attribute__((ext_vector_type(8)));
typedef __bf16 bf16x4 __attribute__((ext_vector_type(4)));
typedef float f32x4 __attribute__((ext_vector_type(4)));

__device__ __forceinline__ void gld_lds16(const __bf16* g, __bf16* l) {
  __builtin_amdgcn_global_load_lds(
      (const __attribute__((address_space(1))) void*)g,
      (__attribute__((address_space(3))) void*)l, 16, 0, 0);
}

// ---------------- LayerNorm: fp32 in, bf16 out ----------------
__global__ __launch_bounds__(256) void ln_kernel(const float* __restrict__ x,
                                                 const float* __restrict__ g,
                                                 const float* __restrict__ b,
                                                 __bf16* __restrict__ out) {
  int row = blockIdx.x;
  const float* xr = x + (size_t)row * D_;
  __bf16* outr = out + (size_t)row * D_;
  int tid = threadIdx.x;

  float4 v = ((const float4*)xr)[tid];
  float s = v.x + v.y + v.z + v.w;
  float ss = v.x * v.x + v.y * v.y + v.z * v.z + v.w * v.w;

  #pragma unroll
  for (int m = 1; m < 64; m <<= 1) {
    s += __shfl_xor(s, m);
    ss += __shfl_xor(ss, m);
  }
  __shared__ float red[10];
  int wid = tid >> 6;
  if ((tid & 63) == 0) { red[wid] = s; red[4 + wid] = ss; }
  __syncthreads();
  if (tid == 0) {
    float ts = red[0] + red[1] + red[2] + red[3];
    float tss = red[4] + red[5] + red[6] + red[7];
    float mu = ts * (1.0f / D_);
    float var = tss * (1.0f / D_) - mu * mu;
    red[8] = mu;
    red[9] = rsqrtf(var + 1e-5f);
  }
  __syncthreads();
  float mu = red[8], rstd = red[9];
  float4 gv = ((const float4*)g)[tid];
  float4 bv = ((const float4*)b)[tid];
  bf16x4 o;
  o[0] = (__bf16)((v.x - mu) * rstd * gv.x + bv.x);
  o[1] = (__bf16)((v.y - mu) * rstd * gv.y + bv.y);
  o[2] = (__bf16)((v.z - mu) * rstd * gv.z + bv.z);
  o[3] = (__bf16)((v.w - mu) * rstd * gv.w + bv.w);
  *(bf16x4*)(outr + tid * 4) = o;
}

// ---------------- Weight transpose+convert: fp32 [1024][1024] -> bf16 [N][K] ----------------
__global__ __launch_bounds__(256) void transpose_w(const float* __restrict__ in,
                                                   __bf16* __restrict__ out) {
  __shared__ float t[64][65];
  const int n0 = blockIdx.x * 64, k0 = blockIdx.y * 64;
  const int tid = threadIdx.x;
  const int r = tid >> 4, c4 = (tid & 15) * 4;
  #pragma unroll
  for (int i = 0; i < 4; ++i) {
    float4 v = *(const float4*)&in[(size_t)(k0 + i * 16 + r) * D_ + n0 + c4];
    t[i * 16 + r][c4 + 0] = v.x;
    t[i * 16 + r][c4 + 1] = v.y;
    t[i * 16 + r][c4 + 2] = v.z;
    t[i * 16 + r][c4 + 3] = v.w;
  }
  __syncthreads();
  #pragma unroll
  for (int i = 0; i < 4; ++i) {
    bf16x4 o;
    #pragma unroll
    for (int j = 0; j < 4; ++j) o[j] = (__bf16)t[c4 + j][i * 16 + r];
    *(bf16x4*)&out[(size_t)(n0 + i * 16 + r) * D_ + k0 + c4] = o;
  }
}

// ---- QKV weights: [H][D][HD] fp32 (x3) -> bf16 rows n = which*1024 + h*64 + e, col k = d ----
__global__ __launch_bounds__(256) void transpose_qkv(const float* __restrict__ Wq,
                                                     const float* __restrict__ Wk,
                                                     const float* __restrict__ Wv,
                                                     __bf16* __restrict__ out) {
  __shared__ float t[64][65];
  const int d0 = blockIdx.x * 64;
  const int h = blockIdx.y;
  const int which = blockIdx.z;
  const float* in = (which == 0 ? Wq : which == 1 ? Wk : Wv) + (size_t)h * D_ * HD_;
  const int tid = threadIdx.x;
  const int r = tid >> 4, c4 = (tid & 15) * 4;
  #pragma unroll
  for (int i = 0; i < 4; ++i) {
    float4 v = *(const float4*)&in[(size_t)(d0 + i * 16 + r) * HD_ + c4];
    t[i * 16 + r][c4 + 0] = v.x;
    t[i * 16 + r][c4 + 1] = v.y;
    t[i * 16 + r][c4 + 2] = v.z;
    t[i * 16 + r][c4 + 3] = v.w;
  }
  __syncthreads();
  #pragma unroll
  for (int i = 0; i < 4; ++i) {
    bf16x4 o;
    #pragma unroll
    for (int j = 0; j < 4; ++j) o[j] = (__bf16)t[c4 + j][i * 16 + r];
    *(bf16x4*)&out[(size_t)(which * 1024 + h * 64 + i * 16 + r) * D_ + d0 + c4] = o;
  }
}

// ---------------- bf16 MFMA GEMM: 128x128 tile, BK=64, XOR-swizzled LDS ----------------
// LDS chunk c (16B) holds A[m0 + (c>>3)][8*((c&7) ^ ((c>>3)&7)) ..+8]: source-permuted
// within each 128B row (coalescing unchanged), read with same XOR -> 2-way banks (free).
#define MODE_QKV 0
#define MODE_PROJ 1
#define MODE_FF1 2
#define MODE_FF2 3

template <int MODE>
__global__ __launch_bounds__(256) void gemm_mfma(const __bf16* __restrict__ A,
                                                 const __bf16* __restrict__ Bt,
                                                 const float* __restrict__ bias,
                                                 const float* __restrict__ resid,
                                                 float* __restrict__ outf,
                                                 __bf16* __restrict__ outb,
                                                 int M, int N, int K) {
  __shared__ __align__(16) __bf16 As[128 * 64];
  __shared__ __align__(16) __bf16 Bs[128 * 64];
  const int tid = threadIdx.x;

  // bijective XCD swizzle (nwg % 8 == 0 for all our grids)
  const int gx = (int)gridDim.x;
  const int nwg = gx * (int)gridDim.y;
  const int flat = (int)blockIdx.y * gx + (int)blockIdx.x;
  const int wg = (flat & 7) * (nwg >> 3) + (flat >> 3);
  const int m0 = (wg / gx) * 128, n0 = (wg % gx) * 128;

  const int w = tid >> 6, l = tid & 63, lr = l & 15, lg = l >> 4;
  const int wm = (w >> 1) * 64, wn = (w & 1) * 64;

  f32x4 acc[4][4] = {};

  for (int k0 = 0; k0 < K; k0 += 64) {
    __syncthreads();
    #pragma unroll
    for (int i = 0; i < 4; ++i) {
      int e = i * 256 + tid;
      int row = e >> 3;
      int col = ((e & 7) ^ (row & 7)) * 8;
      gld_lds16(A + (size_t)(m0 + row) * K + k0 + col, &As[e * 8]);
    }
    #pragma unroll
    for (int i = 0; i < 4; ++i) {
      int e = i * 256 + tid;
      int row = e >> 3;
      int col = ((e & 7) ^ (row & 7)) * 8;
      gld_lds16(Bt + (size_t)(n0 + row) * K + k0 + col, &Bs[e * 8]);
    }
    asm volatile("s_waitcnt vmcnt(0)");
    __syncthreads();

    #pragma unroll
    for (int kk = 0; kk < 2; ++kk) {
      bf16x8 af[4], bfr[4];
      #pragma unroll
      for (int i = 0; i < 4; ++i)
        af[i] = *(const bf16x8*)
            &As[((wm + i * 16 + lr) * 8 + ((kk * 4 + lg) ^ (lr & 7))) * 8];
      #pragma unroll
      for (int j = 0; j < 4; ++j)
        bfr[j] = *(const bf16x8*)
            &Bs[((wn + j * 16 + lr) * 8 + ((kk * 4 + lg) ^ (lr & 7))) * 8];
      #pragma unroll
      for (int i = 0; i < 4; ++i)
        #pragma unroll
        for (int j = 0; j < 4; ++j)
          acc[i][j] = __builtin_amdgcn_mfma_f32_16x16x32_bf16(af[i], bfr[j], acc[i][j], 0, 0, 0);
    }
  }

  #pragma unroll
  for (int i = 0; i < 4; ++i) {
    #pragma unroll
    for (int j = 0; j < 4; ++j) {
      #pragma unroll
      for (int r = 0; r < 4; ++r) {
        int m = m0 + wm + i * 16 + 4 * lg + r;
        int n = n0 + wn + j * 16 + lr;
        float val = acc[i][j][r];
        if (MODE == MODE_QKV) {
          int b = m >> 10, s = m & 1023;
          int which = n >> 10, hh = (n >> 6) & 15, e = n & 63;
          outb[(size_t)which * 8388608 + ((size_t)(b * 16 + hh) * 1024 + s) * 64 + e] =
              (__bf16)val;
        } else if (MODE == MODE_PROJ) {
          size_t idx = (size_t)m * 1024 + n;
          outf[idx] = resid[idx] + val + bias[n];
        } else if (MODE == MODE_FF1) {
          val += bias[n];
          outb[(size_t)m * 1024 + n] =
              (__bf16)(0.5f * val * (1.0f + erff(val * 0.70710678118654752f)));
        } else {
          size_t idx = (size_t)m * 1024 + n;
          outf[idx] = outf[idx] + val + bias[n];
        }
      }
    }
  }
}

// ---------------- Flash attention v4: 8 waves (128 q-rows), XCD-grouped, pipelined --------
// Grid 1024 blocks of 512 thr. bh = (bid&7)*16 + ((bid>>3)&15), qt = bid>>7: all 16 bh of
// one XCD share its L2 (16 x 256KB K/V = 4 MB). Wave w owns q-rows qt*128 + w*16 ..+16.
// K LDS: linear rows + XOR-swizzled 16B chunks (slot ^= row&7): coalesced gld_lds staging,
// conflict-free ds_read_b128. V^T in LDS with permuted t-columns c(t)=[t5 t3 t2 t4 t1 t0];
// PV A-frag = lane's own p-values (no cross-lane P).
__global__ __launch_bounds__(512) void fattn(const __bf16* __restrict__ q,
                                             const __bf16* __restrict__ k,
                                             const __bf16* __restrict__ v,
                                             __bf16* __restrict__ outC) {
  __shared__ __align__(16) __bf16 Klds[2][64 * 64];  // [buf][row*8 + slot^(row&7)] 16B chunks
  __shared__ __align__(16) __bf16 Vp[2][64][72];     // [buf][e][c] permuted V^T

  const int bid = blockIdx.x;
  const int bh = (bid & 7) * 16 + ((bid >> 3) & 15);
  const int qt = bid >> 7;  // 0..7
  const int tid = threadIdx.x;
  const int w = tid >> 6, l = tid & 63;
  const int lr = l & 15, lg = l >> 4;

  const size_t base = (size_t)bh * (S_ * HD_);
  const int qrow0 = qt * 128 + w * 16;
  const __bf16* kg = k + base;
  const __bf16* vg = v + base;

  // K staging geometry: thread stages 16B chunk e=tid: row=tid>>3, source col-chunk XOR'd
  const int krow = tid >> 3;
  const int kcol = ((tid & 7) ^ (krow & 7)) * 8;
  // V staging (waves 0-3 only): source row l, col w*16; permuted dest column
  const int vc = (l & 0x20) + ((l & 0xC) << 1) + ((l & 0x10) >> 2) + (l & 3);

  // Q B-frags, pre-scaled by 1/8 (exact in bf16)
  bf16x8 qf0, qf1;
  {
    const __bf16* qp = q + base + (size_t)(qrow0 + lr) * HD_ + lg * 8;
    qf0 = *(const bf16x8*)(qp);
    qf1 = *(const bf16x8*)(qp + 32);
    #pragma unroll
    for (int i = 0; i < 8; ++i) qf0[i] = (__bf16)((float)qf0[i] * 0.125f);
    #pragma unroll
    for (int i = 0; i < 8; ++i) qf1[i] = (__bf16)((float)qf1[i] * 0.125f);
  }

  f32x4 oacc[4] = {{0,0,0,0},{0,0,0,0},{0,0,0,0},{0,0,0,0}};
  float m_run = -1e30f, l_run = 0.f;

  // ---- prologue: stage K(0); write V(0); load V(1) ----
  gld_lds16(kg + (size_t)krow * HD_ + kcol, &Klds[0][tid * 8]);
  bf16x8 vr0, vr1;
  if (w < 4) {
    const __bf16* vp = vg + (size_t)l * HD_ + w * 16;
    vr0 = *(const bf16x8*)vp;
    vr1 = *(const bf16x8*)(vp + 8);
    #pragma unroll
    for (int i = 0; i < 8; ++i) Vp[0][w * 16 + i][vc] = vr0[i];
    #pragma unroll
    for (int i = 0; i < 8; ++i) Vp[0][w * 16 + 8 + i][vc] = vr1[i];
    const __bf16* vp1 = vg + (size_t)(64 + l) * HD_ + w * 16;
    vr0 = *(const bf16x8*)vp1;
    vr1 = *(const bf16x8*)(vp1 + 8);
  }
  asm volatile("s_waitcnt vmcnt(0)");
  __syncthreads();

  int cur = 0;
  for (int t = 0; t < 16; ++t) {
    // ---- stage K(t+1) into Klds[cur^1] (clamped; last write unread) ----
    {
      int tn = (t < 15) ? (t + 1) : 15;
      gld_lds16(kg + ((size_t)tn * 64 + krow) * HD_ + kcol, &Klds[cur ^ 1][tid * 8]);
    }

    // ---- QK: S^T = mfma(K, Q) from Klds[cur] (XOR-swizzled reads) ----
    f32x4 sacc[4];
    const __bf16* kb = &Klds[cur][0];
    __builtin_amdgcn_s_setprio(1);
    #pragma unroll
    for (int g = 0; g < 4; ++g) {
      bf16x8 kf0 = *(const bf16x8*)&kb[((16 * g + lr) * 8 + (lg ^ (lr & 7))) * 8];
      bf16x8 kf1 = *(const bf16x8*)&kb[((16 * g + lr) * 8 + ((lg + 4) ^ (lr & 7))) * 8];
      f32x4 z = {0.f, 0.f, 0.f, 0.f};
      z = __builtin_amdgcn_mfma_f32_16x16x32_bf16(kf0, qf0, z, 0, 0, 0);
      sacc[g] = __builtin_amdgcn_mfma_f32_16x16x32_bf16(kf1, qf1, z, 0, 0, 0);
    }
    __builtin_amdgcn_s_setprio(0);

    // ---- online softmax (lane-local 16 + 2 shfl) ----
    float tm = sacc[0][0];
    #pragma unroll
    for (int g = 0; g < 4; ++g)
      #pragma unroll
      for (int r = 0; r < 4; ++r) tm = fmaxf(tm, sacc[g][r]);
    tm = fmaxf(tm, __shfl_xor(tm, 16));
    tm = fmaxf(tm, __shfl_xor(tm, 32));

    if (!__all(tm - m_run <= 8.0f)) {
      float mn = fmaxf(m_run, tm);
      float corr = __expf(m_run - mn);
      m_run = mn;
      l_run *= corr;
      #pragma unroll
      for (int r = 0; r < 4; ++r) {
        float cq = __shfl(corr, 4 * lg + r);
        #pragma unroll
        for (int g = 0; g < 4; ++g) oacc[g][r] *= cq;
      }
    }

    float p[4][4];
    float ps = 0.f;
    #pragma unroll
    for (int g = 0; g < 4; ++g)
      #pragma unroll
      for (int r = 0; r < 4; ++r) {
        p[g][r] = __expf(sacc[g][r] - m_run);
        ps += p[g][r];
      }
    ps += __shfl_xor(ps, 16);
    ps += __shfl_xor(ps, 32);
    l_run += ps;

    // ---- V(t+1): regs -> Vp[cur^1] (loads issued last iter); issue V(t+2) loads ----
    if (w < 4) {
      #pragma unroll
      for (int i = 0; i < 8; ++i) Vp[cur ^ 1][w * 16 + i][vc] = vr0[i];
      #pragma unroll
      for (int i = 0; i < 8; ++i) Vp[cur ^ 1][w * 16 + 8 + i][vc] = vr1[i];
      int tnn = (t < 14) ? (t + 2) : 15;
      const __bf16* vp = vg + ((size_t)tnn * 64 + l) * HD_ + w * 16;
      vr0 = *(const bf16x8*)vp;
      vr1 = *(const bf16x8*)(vp + 8);
    }

    // ---- PV: A-frag = own p-values; B from Vp[cur] ----
    bf16x8 af0, af1;
    #pragma unroll
    for (int j = 0; j < 8; ++j) {
      af0[j] = (__bf16)p[j >> 2][j & 3];
      af1[j] = (__bf16)p[2 + (j >> 2)][j & 3];
    }
    __builtin_amdgcn_s_setprio(1);
    #pragma unroll
    for (int g = 0; g < 4; ++g) {
      bf16x8 vf0 = *(const bf16x8*)&Vp[cur][16 * g + lr][lg * 8];
      bf16x8 vf1 = *(const bf16x8*)&Vp[cur][16 * g + lr][32 + lg * 8];
      oacc[g] = __builtin_amdgcn_mfma_f32_16x16x32_bf16(af0, vf0, oacc[g], 0, 0, 0);
      oacc[g] = __builtin_amdgcn_mfma_f32_16x16x32_bf16(af1, vf1, oacc[g], 0, 0, 0);
    }
    __builtin_amdgcn_s_setprio(0);

    asm volatile("s_waitcnt vmcnt(0)");
    __syncthreads();
    cur ^= 1;
  }

  // ---- epilogue: O[q=4lg+r][e=16g+lr] /= l_run[q]; scatter to concat layout ----
  const int b = bh >> 4, hh = bh & 15;
  #pragma unroll
  for (int r = 0; r < 4; ++r) {
    float linv = 1.0f / __shfl(l_run, 4 * lg + r);
    int srow = qrow0 + 4 * lg + r;
    __bf16* op = outC + ((size_t)(b * S_ + srow)) * D_ + hh * HD_;
    #pragma unroll
    for (int g = 0; g < 4; ++g) op[16 * g + lr] = (__bf16)(oacc[g][r] * linv);
  }
}

extern "C" void kernel_launch(void* const* d_in, const int* in_sizes, int n_in,
                              void* d_out, int out_size, void* d_ws, size_t ws_size,
                              hipStream_t stream) {
  const float* x   = (const float*)d_in[0];
  const float* Wq  = (const float*)d_in[1];
  const float* Wk  = (const float*)d_in[2];
  const float* Wv  = (const float*)d_in[3];
  const float* Wo  = (const float*)d_in[4];
  const float* bo  = (const float*)d_in[5];
  const float* W1  = (const float*)d_in[6];
  const float* b1  = (const float*)d_in[7];
  const float* W2  = (const float*)d_in[8];
  const float* b2  = (const float*)d_in[9];
  const float* g1  = (const float*)d_in[10];
  const float* bl1 = (const float*)d_in[11];
  const float* g2  = (const float*)d_in[12];
  const float* bl2 = (const float*)d_in[13];
  float* out = (float*)d_out;

  const size_t MN = (size_t)B_ * S_ * D_;  // 8388608
  __bf16* h     = (__bf16*)d_ws;
  __bf16* wt    = h + MN;
  __bf16* qkv   = wt + (size_t)6144 * 1024;
  __bf16* attnC = qkv + 3 * MN;
  __bf16* ff1   = attnC + MN;

  __bf16* wqkv_t = wt;
  __bf16* wo_t   = wt + (size_t)3072 * 1024;
  __bf16* w1_t   = wt + (size_t)4096 * 1024;
  __bf16* w2_t   = wt + (size_t)5120 * 1024;

  const int rows = B_ * S_;  // 8192

  ln_kernel<<<rows, 256, 0, stream>>>(x, g1, bl1, h);
  transpose_qkv<<<dim3(16, 16, 3), 256, 0, stream>>>(Wq, Wk, Wv, wqkv_t);
  transpose_w<<<dim3(16, 16), 256, 0, stream>>>(Wo, wo_t);
  transpose_w<<<dim3(16, 16), 256, 0, stream>>>(W1, w1_t);
  transpose_w<<<dim3(16, 16), 256, 0, stream>>>(W2, w2_t);

  gemm_mfma<MODE_QKV><<<dim3(24, 64), 256, 0, stream>>>(
      h, wqkv_t, nullptr, nullptr, nullptr, qkv, rows, 3072, D_);
  fattn<<<1024, 512, 0, stream>>>(qkv, qkv + MN, qkv + 2 * MN, attnC);
  gemm_mfma<MODE_PROJ><<<dim3(8, 64), 256, 0, stream>>>(
      attnC, wo_t, bo, x, out, nullptr, rows, D_, D_);
  ln_kernel<<<rows, 256, 0, stream>>>(out, g2, bl2, h);
  gemm_mfma<MODE_FF1><<<dim3(8, 64), 256, 0, stream>>>(
      h, w1_t, b1, nullptr, nullptr, ff1, rows, D_, D_);
  gemm_mfma<MODE_FF2><<<dim3(8, 64), 256, 0, stream>>>(
      ff1, w2_t, b2, nullptr, out, nullptr, rows, D_, D_);
}

// Round 7
// 253.073 us; speedup vs baseline: 1.4929x; 1.0054x over previous
//
#include <hip/hip_runtime.h>
#include <hip/hip_bf16.h>
#include <math.h>

#define B_ 8
#define S_ 1024
#define D_ 1024
#define H_ 16
#define HD_ 64

typedef __bf16 bf16x8 __attribute__((ext_vector_type(8)));
typedef __bf16 bf16x4 __attribute__((ext_vector_type(4)));
typedef float f32x4 __attribute__((ext_vector_type(4)));

#define FMAX3(a, b, c) fmaxf(fmaxf((a), (b)), (c))

__device__ __forceinline__ void gld_lds16(const __bf16* g, __bf16* l) {
  __builtin_amdgcn_global_load_lds(
      (const __attribute__((address_space(1))) void*)g,
      (__attribute__((address_space(3))) void*)l, 16, 0, 0);
}

// ---------------- LayerNorm: fp32 in, bf16 out ----------------
__global__ __launch_bounds__(256) void ln_kernel(const float* __restrict__ x,
                                                 const float* __restrict__ g,
                                                 const float* __restrict__ b,
                                                 __bf16* __restrict__ out) {
  int row = blockIdx.x;
  const float* xr = x + (size_t)row * D_;
  __bf16* outr = out + (size_t)row * D_;
  int tid = threadIdx.x;

  float4 v = ((const float4*)xr)[tid];
  float s = v.x + v.y + v.z + v.w;
  float ss = v.x * v.x + v.y * v.y + v.z * v.z + v.w * v.w;

  #pragma unroll
  for (int m = 1; m < 64; m <<= 1) {
    s += __shfl_xor(s, m);
    ss += __shfl_xor(ss, m);
  }
  __shared__ float red[10];
  int wid = tid >> 6;
  if ((tid & 63) == 0) { red[wid] = s; red[4 + wid] = ss; }
  __syncthreads();
  if (tid == 0) {
    float ts = red[0] + red[1] + red[2] + red[3];
    float tss = red[4] + red[5] + red[6] + red[7];
    float mu = ts * (1.0f / D_);
    float var = tss * (1.0f / D_) - mu * mu;
    red[8] = mu;
    red[9] = rsqrtf(var + 1e-5f);
  }
  __syncthreads();
  float mu = red[8], rstd = red[9];
  float4 gv = ((const float4*)g)[tid];
  float4 bv = ((const float4*)b)[tid];
  bf16x4 o;
  o[0] = (__bf16)((v.x - mu) * rstd * gv.x + bv.x);
  o[1] = (__bf16)((v.y - mu) * rstd * gv.y + bv.y);
  o[2] = (__bf16)((v.z - mu) * rstd * gv.z + bv.z);
  o[3] = (__bf16)((v.w - mu) * rstd * gv.w + bv.w);
  *(bf16x4*)(outr + tid * 4) = o;
}

// ---------------- Unified weight transpose+convert -> bf16 [N=6144][K=1024] ----------------
// z = 0..2: Wq/Wk/Wv [H][D][HD] -> rows z*1024 + h*64 + hd, cols d
// z = 3..5: Wo/W1/W2 [K][N]     -> rows z*1024 + n,         cols k
__global__ __launch_bounds__(256) void transpose_all(const float* __restrict__ Wq,
                                                     const float* __restrict__ Wk,
                                                     const float* __restrict__ Wv,
                                                     const float* __restrict__ Wo,
                                                     const float* __restrict__ W1,
                                                     const float* __restrict__ W2,
                                                     __bf16* __restrict__ out) {
  __shared__ float t[64][65];
  const int x = blockIdx.x, y = blockIdx.y, z = blockIdx.z;
  const int tid = threadIdx.x;
  const int r = tid >> 4, c4 = (tid & 15) * 4;

  const float* src;
  int stride, orowbase, kbase;
  if (z < 3) {
    const float* W = (z == 0 ? Wq : z == 1 ? Wk : Wv);
    src = W + (size_t)y * (D_ * HD_) + (size_t)(x * 64) * HD_;
    stride = HD_;
    orowbase = z * 1024 + y * 64;
    kbase = x * 64;
  } else {
    const float* W = (z == 3 ? Wo : z == 4 ? W1 : W2);
    src = W + (size_t)(y * 64) * D_ + x * 64;
    stride = D_;
    orowbase = z * 1024 + x * 64;
    kbase = y * 64;
  }

  #pragma unroll
  for (int i = 0; i < 4; ++i) {
    float4 v = *(const float4*)&src[(size_t)(i * 16 + r) * stride + c4];
    t[i * 16 + r][c4 + 0] = v.x;
    t[i * 16 + r][c4 + 1] = v.y;
    t[i * 16 + r][c4 + 2] = v.z;
    t[i * 16 + r][c4 + 3] = v.w;
  }
  __syncthreads();
  #pragma unroll
  for (int i = 0; i < 4; ++i) {
    bf16x4 o;
    #pragma unroll
    for (int j = 0; j < 4; ++j) o[j] = (__bf16)t[c4 + j][i * 16 + r];
    *(bf16x4*)&out[(size_t)(orowbase + i * 16 + r) * 1024 + kbase + c4] = o;
  }
}

// ---------------- bf16 MFMA GEMM: 128x128 tile, BK=64, XOR-swizzled LDS ----------------
#define MODE_QKV 0
#define MODE_PROJ 1
#define MODE_FF1 2
#define MODE_FF2 3

// attention scale folded into Q: 1/8 * log2(e)  (exp2-domain softmax in fattn)
#define QSCALE 0.18033688011112042f

template <int MODE>
__global__ __launch_bounds__(256) void gemm_mfma(const __bf16* __restrict__ A,
                                                 const __bf16* __restrict__ Bt,
                                                 const float* __restrict__ bias,
                                                 const float* __restrict__ resid,
                                                 float* __restrict__ outf,
                                                 __bf16* __restrict__ outb,
                                                 int M, int N, int K) {
  __shared__ __align__(16) __bf16 As[128 * 64];
  __shared__ __align__(16) __bf16 Bs[128 * 64];
  const int tid = threadIdx.x;

  // bijective XCD swizzle (nwg % 8 == 0 for all our grids)
  const int gx = (int)gridDim.x;
  const int nwg = gx * (int)gridDim.y;
  const int flat = (int)blockIdx.y * gx + (int)blockIdx.x;
  const int wg = (flat & 7) * (nwg >> 3) + (flat >> 3);
  const int m0 = (wg / gx) * 128, n0 = (wg % gx) * 128;

  const int w = tid >> 6, l = tid & 63, lr = l & 15, lg = l >> 4;
  const int wm = (w >> 1) * 64, wn = (w & 1) * 64;

  f32x4 acc[4][4] = {};

  for (int k0 = 0; k0 < K; k0 += 64) {
    __syncthreads();
    #pragma unroll
    for (int i = 0; i < 4; ++i) {
      int e = i * 256 + tid;
      int row = e >> 3;
      int col = ((e & 7) ^ (row & 7)) * 8;
      gld_lds16(A + (size_t)(m0 + row) * K + k0 + col, &As[e * 8]);
    }
    #pragma unroll
    for (int i = 0; i < 4; ++i) {
      int e = i * 256 + tid;
      int row = e >> 3;
      int col = ((e & 7) ^ (row & 7)) * 8;
      gld_lds16(Bt + (size_t)(n0 + row) * K + k0 + col, &Bs[e * 8]);
    }
    asm volatile("s_waitcnt vmcnt(0)");
    __syncthreads();

    #pragma unroll
    for (int kk = 0; kk < 2; ++kk) {
      bf16x8 af[4], bfr[4];
      #pragma unroll
      for (int i = 0; i < 4; ++i)
        af[i] = *(const bf16x8*)
            &As[((wm + i * 16 + lr) * 8 + ((kk * 4 + lg) ^ (lr & 7))) * 8];
      #pragma unroll
      for (int j = 0; j < 4; ++j)
        bfr[j] = *(const bf16x8*)
            &Bs[((wn + j * 16 + lr) * 8 + ((kk * 4 + lg) ^ (lr & 7))) * 8];
      #pragma unroll
      for (int i = 0; i < 4; ++i)
        #pragma unroll
        for (int j = 0; j < 4; ++j)
          acc[i][j] = __builtin_amdgcn_mfma_f32_16x16x32_bf16(af[i], bfr[j], acc[i][j], 0, 0, 0);
    }
  }

  #pragma unroll
  for (int i = 0; i < 4; ++i) {
    #pragma unroll
    for (int j = 0; j < 4; ++j) {
      #pragma unroll
      for (int r = 0; r < 4; ++r) {
        int m = m0 + wm + i * 16 + 4 * lg + r;
        int n = n0 + wn + j * 16 + lr;
        float val = acc[i][j][r];
        if (MODE == MODE_QKV) {
          int b = m >> 10, s = m & 1023;
          int which = n >> 10, hh = (n >> 6) & 15, e = n & 63;
          if (which == 0) val *= QSCALE;  // fold attn scale + log2e into Q
          outb[(size_t)which * 8388608 + ((size_t)(b * 16 + hh) * 1024 + s) * 64 + e] =
              (__bf16)val;
        } else if (MODE == MODE_PROJ) {
          size_t idx = (size_t)m * 1024 + n;
          outf[idx] = resid[idx] + val + bias[n];
        } else if (MODE == MODE_FF1) {
          val += bias[n];
          outb[(size_t)m * 1024 + n] =
              (__bf16)(0.5f * val * (1.0f + erff(val * 0.70710678118654752f)));
        } else {
          size_t idx = (size_t)m * 1024 + n;
          outf[idx] = outf[idx] + val + bias[n];
        }
      }
    }
  }
}

// ---------------- Flash attention v5: exp2 softmax, sum-in-MFMA, swizzled Vp ----------------
// Grid 1024 blocks x 512 thr; bh = (bid&7)*16 + ((bid>>3)&15) groups one XCD's L2.
// Q pre-scaled by 1/8*log2e in QKV GEMM -> softmax in exp2 domain.
// S^T = mfma(K,Q); lane (lr,lg) holds S[t=16g+4lg+r][q=lr]; max lane-local + 2 shfl.
// Row-sum via ones-column MFMA into oacc[4] (lanes lr==0). K & Vp LDS chunk-XOR swizzled.
__global__ __launch_bounds__(512) void fattn(const __bf16* __restrict__ q,
                                             const __bf16* __restrict__ k,
                                             const __bf16* __restrict__ v,
                                             __bf16* __restrict__ outC) {
  __shared__ __align__(16) __bf16 Klds[2][64 * 64];  // [row][chunk^(row&7)] 16B chunks
  __shared__ __align__(16) __bf16 Vp[2][64 * 64];    // [e][chunk^(e&7)], col = perm t

  const int bid = blockIdx.x;
  const int bh = (bid & 7) * 16 + ((bid >> 3) & 15);
  const int qt = bid >> 7;  // 0..7
  const int tid = threadIdx.x;
  const int w = tid >> 6, l = tid & 63;
  const int lr = l & 15, lg = l >> 4;

  const size_t base = (size_t)bh * (S_ * HD_);
  const int qrow0 = qt * 128 + w * 16;
  const __bf16* kg = k + base;
  const __bf16* vg = v + base;

  // K staging: thread stages 16B chunk: row=tid>>3, source col-chunk XOR'd
  const int krow = tid >> 3;
  const int kcol = ((tid & 7) ^ (krow & 7)) * 8;
  // V staging: all 8 waves; source row t0+l, cols w*8..w*8+7; perm col c(t)=[t5 t3 t2 t4 t1 t0]
  const int vc = (l & 0x20) + ((l & 0xC) << 1) + ((l & 0x10) >> 2) + (l & 3);
  const int vchi = vc >> 3, vclo = vc & 7;

  // Q B-frags (already scaled)
  bf16x8 qf0, qf1;
  {
    const __bf16* qp = q + base + (size_t)(qrow0 + lr) * HD_ + lg * 8;
    qf0 = *(const bf16x8*)(qp);
    qf1 = *(const bf16x8*)(qp + 32);
  }

  // ones B-frag for row-sum column (col 64 -> lanes lr==0)
  const __bf16 onev = (lr == 0) ? (__bf16)1.0f : (__bf16)0.0f;
  const bf16x8 vones = {onev, onev, onev, onev, onev, onev, onev, onev};

  f32x4 oacc[5] = {};
  float m_run = -1e30f;

  // ---- prologue: stage K(0); write V(0); load V(1) ----
  gld_lds16(kg + (size_t)krow * HD_ + kcol, &Klds[0][tid * 8]);
  bf16x8 vr;
  {
    vr = *(const bf16x8*)(vg + (size_t)l * HD_ + w * 8);
    #pragma unroll
    for (int i = 0; i < 8; ++i)
      Vp[0][(w * 8 + i) * 64 + ((vchi ^ i) << 3) + vclo] = vr[i];
    vr = *(const bf16x8*)(vg + (size_t)(64 + l) * HD_ + w * 8);
  }
  asm volatile("s_waitcnt vmcnt(0)");
  __syncthreads();

  int cur = 0;
  for (int t = 0; t < 16; ++t) {
    // ---- stage K(t+1) ----
    {
      int tn = (t < 15) ? (t + 1) : 15;
      gld_lds16(kg + ((size_t)tn * 64 + krow) * HD_ + kcol, &Klds[cur ^ 1][tid * 8]);
    }

    // ---- QK: S^T = mfma(K, Q) ----
    f32x4 sacc[4];
    const __bf16* kb = &Klds[cur][0];
    __builtin_amdgcn_s_setprio(1);
    #pragma unroll
    for (int g = 0; g < 4; ++g) {
      bf16x8 kf0 = *(const bf16x8*)&kb[((16 * g + lr) * 8 + (lg ^ (lr & 7))) * 8];
      bf16x8 kf1 = *(const bf16x8*)&kb[((16 * g + lr) * 8 + ((lg + 4) ^ (lr & 7))) * 8];
      f32x4 z = {0.f, 0.f, 0.f, 0.f};
      z = __builtin_amdgcn_mfma_f32_16x16x32_bf16(kf0, qf0, z, 0, 0, 0);
      sacc[g] = __builtin_amdgcn_mfma_f32_16x16x32_bf16(kf1, qf1, z, 0, 0, 0);
    }
    __builtin_amdgcn_s_setprio(0);

    // ---- online softmax (exp2 domain), max via max3-fuseable tree ----
    float m0 = FMAX3(sacc[0][0], sacc[0][1], sacc[0][2]);
    float m1 = FMAX3(sacc[0][3], sacc[1][0], sacc[1][1]);
    float m2 = FMAX3(sacc[1][2], sacc[1][3], sacc[2][0]);
    float m3 = FMAX3(sacc[2][1], sacc[2][2], sacc[2][3]);
    float m4 = FMAX3(sacc[3][0], sacc[3][1], sacc[3][2]);
    float tm = FMAX3(FMAX3(m0, m1, m2), FMAX3(m3, m4, sacc[3][3]), m_run);
    tm = fmaxf(tm, __shfl_xor(tm, 16));
    tm = fmaxf(tm, __shfl_xor(tm, 32));

    if (!__all(tm - m_run <= 11.5f)) {  // defer-max in log2 units (~8 nats)
      float corr = exp2f(m_run - tm);
      m_run = tm;
      #pragma unroll
      for (int r = 0; r < 4; ++r) {
        float cq = __shfl(corr, 4 * lg + r);
        #pragma unroll
        for (int g = 0; g < 5; ++g) oacc[g][r] *= cq;
      }
    }

    float p[4][4];
    #pragma unroll
    for (int g = 0; g < 4; ++g)
      #pragma unroll
      for (int r = 0; r < 4; ++r) p[g][r] = exp2f(sacc[g][r] - m_run);

    // ---- V(t+1): regs -> Vp[cur^1]; issue V(t+2) loads ----
    #pragma unroll
    for (int i = 0; i < 8; ++i)
      Vp[cur ^ 1][(w * 8 + i) * 64 + ((vchi ^ i) << 3) + vclo] = vr[i];
    {
      int tnn = (t < 14) ? (t + 2) : 15;
      vr = *(const bf16x8*)(vg + ((size_t)tnn * 64 + l) * HD_ + w * 8);
    }

    // ---- PV (+ ones-column row-sum) ----
    bf16x8 af0, af1;
    #pragma unroll
    for (int j = 0; j < 8; ++j) {
      af0[j] = (__bf16)p[j >> 2][j & 3];
      af1[j] = (__bf16)p[2 + (j >> 2)][j & 3];
    }
    __builtin_amdgcn_s_setprio(1);
    #pragma unroll
    for (int g = 0; g < 4; ++g) {
      bf16x8 vf0 = *(const bf16x8*)&Vp[cur][(16 * g + lr) * 64 + ((lg ^ (lr & 7)) << 3)];
      bf16x8 vf1 = *(const bf16x8*)&Vp[cur][(16 * g + lr) * 64 + (((lg + 4) ^ (lr & 7)) << 3)];
      oacc[g] = __builtin_amdgcn_mfma_f32_16x16x32_bf16(af0, vf0, oacc[g], 0, 0, 0);
      oacc[g] = __builtin_amdgcn_mfma_f32_16x16x32_bf16(af1, vf1, oacc[g], 0, 0, 0);
    }
    oacc[4] = __builtin_amdgcn_mfma_f32_16x16x32_bf16(af0, vones, oacc[4], 0, 0, 0);
    oacc[4] = __builtin_amdgcn_mfma_f32_16x16x32_bf16(af1, vones, oacc[4], 0, 0, 0);
    __builtin_amdgcn_s_setprio(0);

    asm volatile("s_waitcnt vmcnt(0)");
    __syncthreads();
    cur ^= 1;
  }

  // ---- epilogue: l-sum lives in oacc[4] at lanes lr==0 (lane 16*lg) ----
  const int b = bh >> 4, hh = bh & 15;
  #pragma unroll
  for (int r = 0; r < 4; ++r) {
    float linv = 1.0f / __shfl(oacc[4][r], l & 48);
    int srow = qrow0 + 4 * lg + r;
    __bf16* op = outC + ((size_t)(b * S_ + srow)) * D_ + hh * HD_;
    #pragma unroll
    for (int g = 0; g < 4; ++g) op[16 * g + lr] = (__bf16)(oacc[g][r] * linv);
  }
}

extern "C" void kernel_launch(void* const* d_in, const int* in_sizes, int n_in,
                              void* d_out, int out_size, void* d_ws, size_t ws_size,
                              hipStream_t stream) {
  const float* x   = (const float*)d_in[0];
  const float* Wq  = (const float*)d_in[1];
  const float* Wk  = (const float*)d_in[2];
  const float* Wv  = (const float*)d_in[3];
  const float* Wo  = (const float*)d_in[4];
  const float* bo  = (const float*)d_in[5];
  const float* W1  = (const float*)d_in[6];
  const float* b1  = (const float*)d_in[7];
  const float* W2  = (const float*)d_in[8];
  const float* b2  = (const float*)d_in[9];
  const float* g1  = (const float*)d_in[10];
  const float* bl1 = (const float*)d_in[11];
  const float* g2  = (const float*)d_in[12];
  const float* bl2 = (const float*)d_in[13];
  float* out = (float*)d_out;

  const size_t MN = (size_t)B_ * S_ * D_;  // 8388608
  __bf16* h     = (__bf16*)d_ws;
  __bf16* wt    = h + MN;                  // 6144 x 1024 bf16 transposed weights
  __bf16* qkv   = wt + (size_t)6144 * 1024;
  __bf16* attnC = qkv + 3 * MN;
  __bf16* ff1   = attnC + MN;

  __bf16* wqkv_t = wt;                       // rows 0..3071
  __bf16* wo_t   = wt + (size_t)3072 * 1024;
  __bf16* w1_t   = wt + (size_t)4096 * 1024;
  __bf16* w2_t   = wt + (size_t)5120 * 1024;

  const int rows = B_ * S_;  // 8192

  ln_kernel<<<rows, 256, 0, stream>>>(x, g1, bl1, h);
  transpose_all<<<dim3(16, 16, 6), 256, 0, stream>>>(Wq, Wk, Wv, Wo, W1, W2, wt);

  gemm_mfma<MODE_QKV><<<dim3(24, 64), 256, 0, stream>>>(
      h, wqkv_t, nullptr, nullptr, nullptr, qkv, rows, 3072, D_);
  fattn<<<1024, 512, 0, stream>>>(qkv, qkv + MN, qkv + 2 * MN, attnC);
  gemm_mfma<MODE_PROJ><<<dim3(8, 64), 256, 0, stream>>>(
      attnC, wo_t, bo, x, out, nullptr, rows, D_, D_);
  ln_kernel<<<rows, 256, 0, stream>>>(out, g2, bl2, h);
  gemm_mfma<MODE_FF1><<<dim3(8, 64), 256, 0, stream>>>(
      h, w1_t, b1, nullptr, nullptr, ff1, rows, D_, D_);
  gemm_mfma<MODE_FF2><<<dim3(8, 64), 256, 0, stream>>>(
      ff1, w2_t, b2, nullptr, out, nullptr, rows, D_, D_);
}

// Round 8
// 234.372 us; speedup vs baseline: 1.6121x; 1.0798x over previous
//
#include <hip/hip_runtime.h>
#include <hip/hip_bf16.h>
#include <math.h>

#define B_ 8
#define S_ 1024
#define D_ 1024
#define H_ 16
#define HD_ 64

typedef __bf16 bf16x8 __attribute__((ext_vector_type(8)));
typedef __bf16 bf16x4 __attribute__((ext_vector_type(4)));
typedef float f32x4 __attribute__((ext_vector_type(4)));

#define FMAX3(a, b, c) fmaxf(fmaxf((a), (b)), (c))

__device__ __forceinline__ void gld_lds16(const __bf16* g, __bf16* l) {
  __builtin_amdgcn_global_load_lds(
      (const __attribute__((address_space(1))) void*)g,
      (__attribute__((address_space(3))) void*)l, 16, 0, 0);
}

// ---------------- LayerNorm: fp32 or bf16 in, bf16 out ----------------
__global__ __launch_bounds__(256) void ln_f32(const float* __restrict__ x,
                                              const float* __restrict__ g,
                                              const float* __restrict__ b,
                                              __bf16* __restrict__ out) {
  int row = blockIdx.x;
  const float* xr = x + (size_t)row * D_;
  __bf16* outr = out + (size_t)row * D_;
  int tid = threadIdx.x;

  float4 v = ((const float4*)xr)[tid];
  float s = v.x + v.y + v.z + v.w;
  float ss = v.x * v.x + v.y * v.y + v.z * v.z + v.w * v.w;

  #pragma unroll
  for (int m = 1; m < 64; m <<= 1) {
    s += __shfl_xor(s, m);
    ss += __shfl_xor(ss, m);
  }
  __shared__ float red[10];
  int wid = tid >> 6;
  if ((tid & 63) == 0) { red[wid] = s; red[4 + wid] = ss; }
  __syncthreads();
  if (tid == 0) {
    float ts = red[0] + red[1] + red[2] + red[3];
    float tss = red[4] + red[5] + red[6] + red[7];
    float mu = ts * (1.0f / D_);
    float var = tss * (1.0f / D_) - mu * mu;
    red[8] = mu;
    red[9] = rsqrtf(var + 1e-5f);
  }
  __syncthreads();
  float mu = red[8], rstd = red[9];
  float4 gv = ((const float4*)g)[tid];
  float4 bv = ((const float4*)b)[tid];
  bf16x4 o;
  o[0] = (__bf16)((v.x - mu) * rstd * gv.x + bv.x);
  o[1] = (__bf16)((v.y - mu) * rstd * gv.y + bv.y);
  o[2] = (__bf16)((v.z - mu) * rstd * gv.z + bv.z);
  o[3] = (__bf16)((v.w - mu) * rstd * gv.w + bv.w);
  *(bf16x4*)(outr + tid * 4) = o;
}

__global__ __launch_bounds__(256) void ln_bf16(const __bf16* __restrict__ x,
                                               const float* __restrict__ g,
                                               const float* __restrict__ b,
                                               __bf16* __restrict__ out) {
  int row = blockIdx.x;
  const __bf16* xr = x + (size_t)row * D_;
  __bf16* outr = out + (size_t)row * D_;
  int tid = threadIdx.x;

  bf16x4 xv = *(const bf16x4*)(xr + tid * 4);
  float v0 = (float)xv[0], v1 = (float)xv[1], v2 = (float)xv[2], v3 = (float)xv[3];
  float s = v0 + v1 + v2 + v3;
  float ss = v0 * v0 + v1 * v1 + v2 * v2 + v3 * v3;

  #pragma unroll
  for (int m = 1; m < 64; m <<= 1) {
    s += __shfl_xor(s, m);
    ss += __shfl_xor(ss, m);
  }
  __shared__ float red[10];
  int wid = tid >> 6;
  if ((tid & 63) == 0) { red[wid] = s; red[4 + wid] = ss; }
  __syncthreads();
  if (tid == 0) {
    float ts = red[0] + red[1] + red[2] + red[3];
    float tss = red[4] + red[5] + red[6] + red[7];
    float mu = ts * (1.0f / D_);
    float var = tss * (1.0f / D_) - mu * mu;
    red[8] = mu;
    red[9] = rsqrtf(var + 1e-5f);
  }
  __syncthreads();
  float mu = red[8], rstd = red[9];
  float4 gv = ((const float4*)g)[tid];
  float4 bv = ((const float4*)b)[tid];
  bf16x4 o;
  o[0] = (__bf16)((v0 - mu) * rstd * gv.x + bv.x);
  o[1] = (__bf16)((v1 - mu) * rstd * gv.y + bv.y);
  o[2] = (__bf16)((v2 - mu) * rstd * gv.z + bv.z);
  o[3] = (__bf16)((v3 - mu) * rstd * gv.w + bv.w);
  *(bf16x4*)(outr + tid * 4) = o;
}

// ---------------- Unified weight transpose+convert -> bf16 [N=6144][K=1024] ----------------
__global__ __launch_bounds__(256) void transpose_all(const float* __restrict__ Wq,
                                                     const float* __restrict__ Wk,
                                                     const float* __restrict__ Wv,
                                                     const float* __restrict__ Wo,
                                                     const float* __restrict__ W1,
                                                     const float* __restrict__ W2,
                                                     __bf16* __restrict__ out) {
  __shared__ float t[64][65];
  const int x = blockIdx.x, y = blockIdx.y, z = blockIdx.z;
  const int tid = threadIdx.x;
  const int r = tid >> 4, c4 = (tid & 15) * 4;

  const float* src;
  int stride, orowbase, kbase;
  if (z < 3) {
    const float* W = (z == 0 ? Wq : z == 1 ? Wk : Wv);
    src = W + (size_t)y * (D_ * HD_) + (size_t)(x * 64) * HD_;
    stride = HD_;
    orowbase = z * 1024 + y * 64;
    kbase = x * 64;
  } else {
    const float* W = (z == 3 ? Wo : z == 4 ? W1 : W2);
    src = W + (size_t)(y * 64) * D_ + x * 64;
    stride = D_;
    orowbase = z * 1024 + x * 64;
    kbase = y * 64;
  }

  #pragma unroll
  for (int i = 0; i < 4; ++i) {
    float4 v = *(const float4*)&src[(size_t)(i * 16 + r) * stride + c4];
    t[i * 16 + r][c4 + 0] = v.x;
    t[i * 16 + r][c4 + 1] = v.y;
    t[i * 16 + r][c4 + 2] = v.z;
    t[i * 16 + r][c4 + 3] = v.w;
  }
  __syncthreads();
  #pragma unroll
  for (int i = 0; i < 4; ++i) {
    bf16x4 o;
    #pragma unroll
    for (int j = 0; j < 4; ++j) o[j] = (__bf16)t[c4 + j][i * 16 + r];
    *(bf16x4*)&out[(size_t)(orowbase + i * 16 + r) * 1024 + kbase + c4] = o;
  }
}

// ---------------- bf16 MFMA GEMM: 128x128 tile, BK=64, XOR-swizzled LDS ----------------
#define MODE_QKV 0
#define MODE_PROJ 1
#define MODE_FF1 2
#define MODE_FF2 3

// attention scale folded into Q: 1/8 * log2(e)  (exp2-domain softmax in fattn)
#define QSCALE 0.18033688011112042f

template <int MODE>
__global__ __launch_bounds__(256) void gemm_mfma(const __bf16* __restrict__ A,
                                                 const __bf16* __restrict__ Bt,
                                                 const float* __restrict__ bias,
                                                 const float* __restrict__ residf,
                                                 const __bf16* __restrict__ residb,
                                                 float* __restrict__ outf,
                                                 __bf16* __restrict__ outb,
                                                 int M, int N, int K) {
  __shared__ __align__(16) __bf16 As[128 * 64];
  __shared__ __align__(16) __bf16 Bs[128 * 64];
  const int tid = threadIdx.x;

  // bijective XCD swizzle (nwg % 8 == 0 for all our grids)
  const int gx = (int)gridDim.x;
  const int nwg = gx * (int)gridDim.y;
  const int flat = (int)blockIdx.y * gx + (int)blockIdx.x;
  const int wg = (flat & 7) * (nwg >> 3) + (flat >> 3);
  const int m0 = (wg / gx) * 128, n0 = (wg % gx) * 128;

  const int w = tid >> 6, l = tid & 63, lr = l & 15, lg = l >> 4;
  const int wm = (w >> 1) * 64, wn = (w & 1) * 64;

  f32x4 acc[4][4] = {};

  for (int k0 = 0; k0 < K; k0 += 64) {
    __syncthreads();
    #pragma unroll
    for (int i = 0; i < 4; ++i) {
      int e = i * 256 + tid;
      int row = e >> 3;
      int col = ((e & 7) ^ (row & 7)) * 8;
      gld_lds16(A + (size_t)(m0 + row) * K + k0 + col, &As[e * 8]);
    }
    #pragma unroll
    for (int i = 0; i < 4; ++i) {
      int e = i * 256 + tid;
      int row = e >> 3;
      int col = ((e & 7) ^ (row & 7)) * 8;
      gld_lds16(Bt + (size_t)(n0 + row) * K + k0 + col, &Bs[e * 8]);
    }
    asm volatile("s_waitcnt vmcnt(0)");
    __syncthreads();

    #pragma unroll
    for (int kk = 0; kk < 2; ++kk) {
      bf16x8 af[4], bfr[4];
      #pragma unroll
      for (int i = 0; i < 4; ++i)
        af[i] = *(const bf16x8*)
            &As[((wm + i * 16 + lr) * 8 + ((kk * 4 + lg) ^ (lr & 7))) * 8];
      #pragma unroll
      for (int j = 0; j < 4; ++j)
        bfr[j] = *(const bf16x8*)
            &Bs[((wn + j * 16 + lr) * 8 + ((kk * 4 + lg) ^ (lr & 7))) * 8];
      #pragma unroll
      for (int i = 0; i < 4; ++i)
        #pragma unroll
        for (int j = 0; j < 4; ++j)
          acc[i][j] = __builtin_amdgcn_mfma_f32_16x16x32_bf16(af[i], bfr[j], acc[i][j], 0, 0, 0);
    }
  }

  #pragma unroll
  for (int i = 0; i < 4; ++i) {
    #pragma unroll
    for (int j = 0; j < 4; ++j) {
      #pragma unroll
      for (int r = 0; r < 4; ++r) {
        int m = m0 + wm + i * 16 + 4 * lg + r;
        int n = n0 + wn + j * 16 + lr;
        float val = acc[i][j][r];
        if (MODE == MODE_QKV) {
          int b = m >> 10, s = m & 1023;
          int which = n >> 10, hh = (n >> 6) & 15, e = n & 63;
          if (which == 0) val *= QSCALE;  // fold attn scale + log2e into Q
          outb[(size_t)which * 8388608 + ((size_t)(b * 16 + hh) * 1024 + s) * 64 + e] =
              (__bf16)val;
        } else if (MODE == MODE_PROJ) {
          size_t idx = (size_t)m * 1024 + n;
          outb[idx] = (__bf16)(residf[idx] + val + bias[n]);  // bf16 mid residual
        } else if (MODE == MODE_FF1) {
          val += bias[n];
          outb[(size_t)m * 1024 + n] =
              (__bf16)(0.5f * val * (1.0f + erff(val * 0.70710678118654752f)));
        } else {  // FF2: final fp32 out = bf16 mid + val + bias
          size_t idx = (size_t)m * 1024 + n;
          outf[idx] = (float)residb[idx] + val + bias[n];
        }
      }
    }
  }
}

// ---------------- Flash attention v6: counted-vmcnt pipeline, raw barrier ----------------
// Grid 1024 blocks x 512 thr; bh = (bid&7)*16 + ((bid>>3)&15) groups one XCD's L2.
// Q pre-scaled by 1/8*log2e -> exp2-domain softmax (__builtin_amdgcn_exp2f = raw v_exp).
// S^T = mfma(K,Q); lane (lr,lg) holds S[t=16g+4lg+r][q=lr]; max lane-local + 2 shfl.
// Row-sum via ones-column MFMA into oacc[4]. K & Vp LDS chunk-XOR swizzled (0 conflicts).
// End-of-iter: s_waitcnt vmcnt(1) drains ONLY K's gld_lds (V(t+2) stays in flight across
// the raw s_barrier) — T4 counted-vmcnt; __syncthreads would force vmcnt(0).
__global__ __launch_bounds__(512) void fattn(const __bf16* __restrict__ q,
                                             const __bf16* __restrict__ k,
                                             const __bf16* __restrict__ v,
                                             __bf16* __restrict__ outC) {
  __shared__ __align__(16) __bf16 Klds[2][64 * 64];  // [row][chunk^(row&7)] 16B chunks
  __shared__ __align__(16) __bf16 Vp[2][64 * 64];    // [e][chunk^(e&7)], col = perm t

  const int bid = blockIdx.x;
  const int bh = (bid & 7) * 16 + ((bid >> 3) & 15);
  const int qt = bid >> 7;  // 0..7
  const int tid = threadIdx.x;
  const int w = tid >> 6, l = tid & 63;
  const int lr = l & 15, lg = l >> 4;

  const size_t base = (size_t)bh * (S_ * HD_);
  const int qrow0 = qt * 128 + w * 16;
  const __bf16* kg = k + base;
  const __bf16* vg = v + base;

  const int krow = tid >> 3;
  const int kcol = ((tid & 7) ^ (krow & 7)) * 8;
  const int vc = (l & 0x20) + ((l & 0xC) << 1) + ((l & 0x10) >> 2) + (l & 3);
  const int vchi = vc >> 3, vclo = vc & 7;

  bf16x8 qf0, qf1;
  {
    const __bf16* qp = q + base + (size_t)(qrow0 + lr) * HD_ + lg * 8;
    qf0 = *(const bf16x8*)(qp);
    qf1 = *(const bf16x8*)(qp + 32);
  }

  const __bf16 onev = (lr == 0) ? (__bf16)1.0f : (__bf16)0.0f;
  const bf16x8 vones = {onev, onev, onev, onev, onev, onev, onev, onev};

  f32x4 oacc[5] = {};
  float m_run = -1e30f;

  // ---- prologue: stage K(0); write V(0); load V(1) ----
  gld_lds16(kg + (size_t)krow * HD_ + kcol, &Klds[0][tid * 8]);
  bf16x8 vr;
  {
    vr = *(const bf16x8*)(vg + (size_t)l * HD_ + w * 8);
    #pragma unroll
    for (int i = 0; i < 8; ++i)
      Vp[0][(w * 8 + i) * 64 + ((vchi ^ i) << 3) + vclo] = vr[i];
    vr = *(const bf16x8*)(vg + (size_t)(64 + l) * HD_ + w * 8);
  }
  asm volatile("s_waitcnt vmcnt(1) lgkmcnt(0)" ::: "memory");  // K(0) done; V(1) in flight
  __builtin_amdgcn_sched_barrier(0);
  __builtin_amdgcn_s_barrier();
  __builtin_amdgcn_sched_barrier(0);

  int cur = 0;
  for (int t = 0; t < 16; ++t) {
    // ---- stage K(t+1) (full iteration of cover) ----
    {
      int tn = (t < 15) ? (t + 1) : 15;
      gld_lds16(kg + ((size_t)tn * 64 + krow) * HD_ + kcol, &Klds[cur ^ 1][tid * 8]);
    }

    // ---- QK: S^T = mfma(K, Q) ----
    f32x4 sacc[4];
    const __bf16* kb = &Klds[cur][0];
    __builtin_amdgcn_s_setprio(1);
    #pragma unroll
    for (int g = 0; g < 4; ++g) {
      bf16x8 kf0 = *(const bf16x8*)&kb[((16 * g + lr) * 8 + (lg ^ (lr & 7))) * 8];
      bf16x8 kf1 = *(const bf16x8*)&kb[((16 * g + lr) * 8 + ((lg + 4) ^ (lr & 7))) * 8];
      f32x4 z = {0.f, 0.f, 0.f, 0.f};
      z = __builtin_amdgcn_mfma_f32_16x16x32_bf16(kf0, qf0, z, 0, 0, 0);
      sacc[g] = __builtin_amdgcn_mfma_f32_16x16x32_bf16(kf1, qf1, z, 0, 0, 0);
    }
    __builtin_amdgcn_s_setprio(0);

    // ---- V(t+1): regs -> Vp[cur^1]; issue V(t+2) loads (max cover) ----
    #pragma unroll
    for (int i = 0; i < 8; ++i)
      Vp[cur ^ 1][(w * 8 + i) * 64 + ((vchi ^ i) << 3) + vclo] = vr[i];
    {
      int tnn = (t < 14) ? (t + 2) : 15;
      vr = *(const bf16x8*)(vg + ((size_t)tnn * 64 + l) * HD_ + w * 8);
    }

    // ---- online softmax (exp2 domain, raw v_exp) ----
    float m0 = FMAX3(sacc[0][0], sacc[0][1], sacc[0][2]);
    float m1 = FMAX3(sacc[0][3], sacc[1][0], sacc[1][1]);
    float m2 = FMAX3(sacc[1][2], sacc[1][3], sacc[2][0]);
    float m3 = FMAX3(sacc[2][1], sacc[2][2], sacc[2][3]);
    float m4 = FMAX3(sacc[3][0], sacc[3][1], sacc[3][2]);
    float tm = FMAX3(FMAX3(m0, m1, m2), FMAX3(m3, m4, sacc[3][3]), m_run);
    tm = fmaxf(tm, __shfl_xor(tm, 16));
    tm = fmaxf(tm, __shfl_xor(tm, 32));

    if (!__all(tm - m_run <= 11.5f)) {  // defer-max in log2 units
      float corr = __builtin_amdgcn_exp2f(m_run - tm);
      m_run = tm;
      #pragma unroll
      for (int r = 0; r < 4; ++r) {
        float cq = __shfl(corr, 4 * lg + r);
        #pragma unroll
        for (int g = 0; g < 5; ++g) oacc[g][r] *= cq;
      }
    }

    float p[4][4];
    #pragma unroll
    for (int g = 0; g < 4; ++g)
      #pragma unroll
      for (int r = 0; r < 4; ++r)
        p[g][r] = __builtin_amdgcn_exp2f(sacc[g][r] - m_run);

    // ---- PV (+ ones-column row-sum) ----
    bf16x8 af0, af1;
    #pragma unroll
    for (int j = 0; j < 8; ++j) {
      af0[j] = (__bf16)p[j >> 2][j & 3];
      af1[j] = (__bf16)p[2 + (j >> 2)][j & 3];
    }
    __builtin_amdgcn_s_setprio(1);
    #pragma unroll
    for (int g = 0; g < 4; ++g) {
      bf16x8 vf0 = *(const bf16x8*)&Vp[cur][(16 * g + lr) * 64 + ((lg ^ (lr & 7)) << 3)];
      bf16x8 vf1 = *(const bf16x8*)&Vp[cur][(16 * g + lr) * 64 + (((lg + 4) ^ (lr & 7)) << 3)];
      oacc[g] = __builtin_amdgcn_mfma_f32_16x16x32_bf16(af0, vf0, oacc[g], 0, 0, 0);
      oacc[g] = __builtin_amdgcn_mfma_f32_16x16x32_bf16(af1, vf1, oacc[g], 0, 0, 0);
    }
    oacc[4] = __builtin_amdgcn_mfma_f32_16x16x32_bf16(af0, vones, oacc[4], 0, 0, 0);
    oacc[4] = __builtin_amdgcn_mfma_f32_16x16x32_bf16(af1, vones, oacc[4], 0, 0, 0);
    __builtin_amdgcn_s_setprio(0);

    // ---- counted drain: K(t+1) done, V(t+2) stays in flight across barrier ----
    asm volatile("s_waitcnt vmcnt(1) lgkmcnt(0)" ::: "memory");
    __builtin_amdgcn_sched_barrier(0);
    __builtin_amdgcn_s_barrier();
    __builtin_amdgcn_sched_barrier(0);
    cur ^= 1;
  }

  // ---- epilogue: l-sum lives in oacc[4] at lanes lr==0 (lane 16*lg) ----
  const int b = bh >> 4, hh = bh & 15;
  #pragma unroll
  for (int r = 0; r < 4; ++r) {
    float linv = 1.0f / __shfl(oacc[4][r], l & 48);
    int srow = qrow0 + 4 * lg + r;
    __bf16* op = outC + ((size_t)(b * S_ + srow)) * D_ + hh * HD_;
    #pragma unroll
    for (int g = 0; g < 4; ++g) op[16 * g + lr] = (__bf16)(oacc[g][r] * linv);
  }
}

extern "C" void kernel_launch(void* const* d_in, const int* in_sizes, int n_in,
                              void* d_out, int out_size, void* d_ws, size_t ws_size,
                              hipStream_t stream) {
  const float* x   = (const float*)d_in[0];
  const float* Wq  = (const float*)d_in[1];
  const float* Wk  = (const float*)d_in[2];
  const float* Wv  = (const float*)d_in[3];
  const float* Wo  = (const float*)d_in[4];
  const float* bo  = (const float*)d_in[5];
  const float* W1  = (const float*)d_in[6];
  const float* b1  = (const float*)d_in[7];
  const float* W2  = (const float*)d_in[8];
  const float* b2  = (const float*)d_in[9];
  const float* g1  = (const float*)d_in[10];
  const float* bl1 = (const float*)d_in[11];
  const float* g2  = (const float*)d_in[12];
  const float* bl2 = (const float*)d_in[13];
  float* out = (float*)d_out;

  const size_t MN = (size_t)B_ * S_ * D_;  // 8388608
  __bf16* h     = (__bf16*)d_ws;
  __bf16* wt    = h + MN;                  // 6144 x 1024 bf16 transposed weights
  __bf16* qkv   = wt + (size_t)6144 * 1024;
  __bf16* attnC = qkv + 3 * MN;
  __bf16* ff1   = attnC + MN;
  __bf16* mid   = ff1 + MN;                // bf16 residual (x + sa)

  __bf16* wqkv_t = wt;
  __bf16* wo_t   = wt + (size_t)3072 * 1024;
  __bf16* w1_t   = wt + (size_t)4096 * 1024;
  __bf16* w2_t   = wt + (size_t)5120 * 1024;

  const int rows = B_ * S_;  // 8192

  ln_f32<<<rows, 256, 0, stream>>>(x, g1, bl1, h);
  transpose_all<<<dim3(16, 16, 6), 256, 0, stream>>>(Wq, Wk, Wv, Wo, W1, W2, wt);

  gemm_mfma<MODE_QKV><<<dim3(24, 64), 256, 0, stream>>>(
      h, wqkv_t, nullptr, nullptr, nullptr, nullptr, qkv, rows, 3072, D_);
  fattn<<<1024, 512, 0, stream>>>(qkv, qkv + MN, qkv + 2 * MN, attnC);
  gemm_mfma<MODE_PROJ><<<dim3(8, 64), 256, 0, stream>>>(
      attnC, wo_t, bo, x, nullptr, nullptr, mid, rows, D_, D_);
  ln_bf16<<<rows, 256, 0, stream>>>(mid, g2, bl2, h);
  gemm_mfma<MODE_FF1><<<dim3(8, 64), 256, 0, stream>>>(
      h, w1_t, b1, nullptr, nullptr, nullptr, ff1, rows, D_, D_);
  gemm_mfma<MODE_FF2><<<dim3(8, 64), 256, 0, stream>>>(
      ff1, w2_t, b2, nullptr, mid, out, nullptr, rows, D_, D_);
}